// Round 1
// baseline (3609.396 us; speedup 1.0000x reference)
//
#include <hip/hip_runtime.h>
#include <math.h>

#define NN 8192

__device__ __forceinline__ float fast_sigexp(float x) {
    // exp(sigmoid(x)); sigmoid in (0,1) so no range issues
    float s = __builtin_amdgcn_rcpf(1.0f + __expf(-x));
    return __expf(s);
}

// ---------------- projection: Z = relu(H @ W^T + b) ----------------
// H: [N,K] row-major, W: [O,K] row-major, Z: [N,O]. 64x64 tile, BK=16, 4x4/thread.
__global__ __launch_bounds__(256) void proj_gemm(
    const float* __restrict__ H, const float* __restrict__ W,
    const float* __restrict__ bias, float* __restrict__ Z,
    int K, int O)
{
    __shared__ float Hs[64][17];
    __shared__ float Ws[64][17];
    const int tid = threadIdx.x;
    const int i0 = blockIdx.y * 64;
    const int o0 = blockIdx.x * 64;
    const int tx = tid & 15;        // o micro
    const int ty = tid >> 4;        // i micro
    const int lr = tid >> 2;        // load row 0..63
    const int lc = (tid & 3) << 2;  // load col 0,4,8,12
    const float* Hp = H + (size_t)(i0 + lr) * K + lc;
    const float* Wp = W + (size_t)(o0 + lr) * K + lc;
    float acc[4][4] = {};
    for (int k0 = 0; k0 < K; k0 += 16) {
        float4 h4 = *(const float4*)(Hp + k0);
        float4 w4 = *(const float4*)(Wp + k0);
        Hs[lr][lc+0] = h4.x; Hs[lr][lc+1] = h4.y; Hs[lr][lc+2] = h4.z; Hs[lr][lc+3] = h4.w;
        Ws[lr][lc+0] = w4.x; Ws[lr][lc+1] = w4.y; Ws[lr][lc+2] = w4.z; Ws[lr][lc+3] = w4.w;
        __syncthreads();
        #pragma unroll
        for (int k = 0; k < 16; ++k) {
            float a[4], b[4];
            #pragma unroll
            for (int u = 0; u < 4; ++u) a[u] = Hs[ty*4+u][k];
            #pragma unroll
            for (int v = 0; v < 4; ++v) b[v] = Ws[tx*4+v][k];
            #pragma unroll
            for (int u = 0; u < 4; ++u)
                #pragma unroll
                for (int v = 0; v < 4; ++v)
                    acc[u][v] = fmaf(a[u], b[v], acc[u][v]);
        }
        __syncthreads();
    }
    #pragma unroll
    for (int u = 0; u < 4; ++u) {
        int i = i0 + ty*4 + u;
        float4 o4;
        o4.x = fmaxf(acc[u][0] + bias[o0 + tx*4 + 0], 0.f);
        o4.y = fmaxf(acc[u][1] + bias[o0 + tx*4 + 1], 0.f);
        o4.z = fmaxf(acc[u][2] + bias[o0 + tx*4 + 2], 0.f);
        o4.w = fmaxf(acc[u][3] + bias[o0 + tx*4 + 3], 0.f);
        *(float4*)(Z + (size_t)i * O + o0 + tx*4) = o4;
    }
}

// ---------------- t,r: per-row dots ----------------
__global__ __launch_bounds__(256) void tr_kernel(
    const float* __restrict__ Z,
    const float* __restrict__ tw, const float* __restrict__ tb,
    const float* __restrict__ rw, const float* __restrict__ rb,
    float* __restrict__ t, float* __restrict__ r, int O)
{
    const int wave = threadIdx.x >> 6;
    const int lane = threadIdx.x & 63;
    const int row  = blockIdx.x * 4 + wave;
    const float* z = Z + (size_t)row * O;
    float at = 0.f, ar = 0.f;
    for (int c = lane; c < O; c += 64) {
        float zv = z[c];
        at = fmaf(zv, tw[c], at);
        ar = fmaf(zv, rw[c], ar);
    }
    #pragma unroll
    for (int off = 32; off; off >>= 1) {
        at += __shfl_down(at, off);
        ar += __shfl_down(ar, off);
    }
    if (lane == 0) { t[row] = at + tb[0]; r[row] = ar + rb[0]; }
}

// ---------------- denom[i] = sum_j exp(sigmoid(A[i,j]*t[j] + A[j,i]*r[i])) ----------------
__global__ __launch_bounds__(256) void denom_kernel(
    const float* __restrict__ A, const float* __restrict__ t,
    const float* __restrict__ r, float* __restrict__ denom)
{
    __shared__ float Aij[64][65];
    __shared__ float Aji[64][65];
    __shared__ float ts[64];
    __shared__ float red[4][64];
    const int tid = threadIdx.x;
    const int i0 = blockIdx.x * 64;
    const int li = tid & 63;        // compute-phase i
    const int jq = tid >> 6;        // j quarter
    const int lr = tid >> 4;        // 0..15
    const int lc = (tid & 15) << 2; // 0..60
    const float ri = r[i0 + li];
    float acc = 0.f;
    for (int j0 = 0; j0 < NN; j0 += 64) {
        if (tid < 64) ts[tid] = t[j0 + tid];
        #pragma unroll
        for (int rep = 0; rep < 4; ++rep) {
            int row = rep*16 + lr;
            float4 a4 = *(const float4*)(A + (size_t)(i0 + row) * NN + j0 + lc);
            Aij[row][lc+0] = a4.x; Aij[row][lc+1] = a4.y; Aij[row][lc+2] = a4.z; Aij[row][lc+3] = a4.w;
            float4 b4 = *(const float4*)(A + (size_t)(j0 + row) * NN + i0 + lc);
            Aji[row][lc+0] = b4.x; Aji[row][lc+1] = b4.y; Aji[row][lc+2] = b4.z; Aji[row][lc+3] = b4.w;
        }
        __syncthreads();
        #pragma unroll
        for (int jj = 0; jj < 16; ++jj) {
            int j = jq*16 + jj;
            float x = fmaf(Aij[li][j], ts[j], Aji[j][li] * ri);
            acc += fast_sigexp(x);
        }
        __syncthreads();
    }
    red[jq][li] = acc;
    __syncthreads();
    if (tid < 64)
        denom[i0 + tid] = red[0][tid] + red[1][tid] + red[2][tid] + red[3][tid];
}

// ---------------- fused attention GEMM: Hout[i,c] = (1/denom[i]) * sum_j P(i,j)*Z[j,c] ----------------
__global__ __launch_bounds__(256) void attn_gemm(
    const float* __restrict__ A, const float* __restrict__ Z,
    const float* __restrict__ t, const float* __restrict__ r,
    const float* __restrict__ denom, float* __restrict__ Hout, int O)
{
    __shared__ float Pt[64][68];   // Pt[j][i], padded: 272B row -> float4-aligned
    __shared__ float Zs[64][68];   // Zs[j][c]
    __shared__ float Ajs[64][65];  // Ajs[j][i] = A[j0+j][i0+i]
    __shared__ float ts[64];
    __shared__ float rs[64];
    const int tid = threadIdx.x;
    const int i0 = blockIdx.y * 64;
    const int c0 = blockIdx.x * 64;
    const int tx = tid & 15;        // c micro
    const int ty = tid >> 4;        // i micro
    const int lr = tid >> 4;        // 0..15
    const int lc = (tid & 15) << 2; // 0..60
    if (tid < 64) rs[tid] = r[i0 + tid];
    float acc[4][4] = {};
    for (int j0 = 0; j0 < NN; j0 += 64) {
        if (tid < 64) ts[tid] = t[j0 + tid];
        #pragma unroll
        for (int rep = 0; rep < 4; ++rep) {
            int row = rep*16 + lr;
            float4 a4 = *(const float4*)(A + (size_t)(j0 + row) * NN + i0 + lc);
            Ajs[row][lc+0] = a4.x; Ajs[row][lc+1] = a4.y; Ajs[row][lc+2] = a4.z; Ajs[row][lc+3] = a4.w;
            float4 z4 = *(const float4*)(Z + (size_t)(j0 + row) * O + c0 + lc);
            *(float4*)&Zs[row][lc] = z4;
        }
        __syncthreads();
        // compute P tile (j-major) from coalesced A-row loads + staged A^T
        #pragma unroll
        for (int rep = 0; rep < 4; ++rep) {
            int i = rep*16 + lr;
            float ri = rs[i];
            float4 a4 = *(const float4*)(A + (size_t)(i0 + i) * NN + j0 + lc);
            Pt[lc+0][i] = fast_sigexp(fmaf(a4.x, ts[lc+0], Ajs[lc+0][i] * ri));
            Pt[lc+1][i] = fast_sigexp(fmaf(a4.y, ts[lc+1], Ajs[lc+1][i] * ri));
            Pt[lc+2][i] = fast_sigexp(fmaf(a4.z, ts[lc+2], Ajs[lc+2][i] * ri));
            Pt[lc+3][i] = fast_sigexp(fmaf(a4.w, ts[lc+3], Ajs[lc+3][i] * ri));
        }
        __syncthreads();
        #pragma unroll
        for (int j = 0; j < 64; ++j) {
            float4 p4 = *(const float4*)&Pt[j][ty*4];
            float4 z4 = *(const float4*)&Zs[j][tx*4];
            float av[4] = {p4.x, p4.y, p4.z, p4.w};
            float bv[4] = {z4.x, z4.y, z4.z, z4.w};
            #pragma unroll
            for (int u = 0; u < 4; ++u)
                #pragma unroll
                for (int v = 0; v < 4; ++v)
                    acc[u][v] = fmaf(av[u], bv[v], acc[u][v]);
        }
        __syncthreads();
    }
    #pragma unroll
    for (int u = 0; u < 4; ++u) {
        int i = i0 + ty*4 + u;
        float inv = __builtin_amdgcn_rcpf(denom[i]);
        float4 o4;
        o4.x = acc[u][0] * inv;
        o4.y = acc[u][1] * inv;
        o4.z = acc[u][2] * inv;
        o4.w = acc[u][3] * inv;
        *(float4*)(Hout + (size_t)i * O + c0 + tx*4) = o4;
    }
}

// ---------------- host-side layer driver ----------------
static void run_layer(const float* H, int K, int O,
                      const float* Ww, const float* Wb,
                      const float* tw, const float* tb,
                      const float* rw, const float* rb,
                      const float* A,
                      float* Z, float* t, float* r, float* denom,
                      float* Hout, hipStream_t stream)
{
    dim3 g1(O / 64, NN / 64);
    proj_gemm<<<g1, 256, 0, stream>>>(H, Ww, Wb, Z, K, O);
    tr_kernel<<<NN / 4, 256, 0, stream>>>(Z, tw, tb, rw, rb, t, r, O);
    denom_kernel<<<NN / 64, 256, 0, stream>>>(A, t, r, denom);
    dim3 g2(O / 64, NN / 64);
    attn_gemm<<<g2, 256, 0, stream>>>(A, Z, t, r, denom, Hout, O);
}

extern "C" void kernel_launch(void* const* d_in, const int* in_sizes, int n_in,
                              void* d_out, int out_size, void* d_ws, size_t ws_size,
                              hipStream_t stream)
{
    (void)in_sizes; (void)n_in; (void)out_size; (void)ws_size;
    const float* X   = (const float*)d_in[0];
    const float* A   = (const float*)d_in[1];
    const float* W1w = (const float*)d_in[2];
    const float* W1b = (const float*)d_in[3];
    const float* t1w = (const float*)d_in[4];
    const float* t1b = (const float*)d_in[5];
    const float* r1w = (const float*)d_in[6];
    const float* r1b = (const float*)d_in[7];
    const float* W2w = (const float*)d_in[8];
    const float* W2b = (const float*)d_in[9];
    const float* t2w = (const float*)d_in[10];
    const float* t2b = (const float*)d_in[11];
    const float* r2w = (const float*)d_in[12];
    const float* r2b = (const float*)d_in[13];
    const float* W3w = (const float*)d_in[14];
    const float* W3b = (const float*)d_in[15];
    const float* t3w = (const float*)d_in[16];
    const float* t3b = (const float*)d_in[17];
    const float* r3w = (const float*)d_in[18];
    const float* r3b = (const float*)d_in[19];
    float* out = (float*)d_out;

    float* ws  = (float*)d_ws;
    float* Zb  = ws;                           // 8192*512 f32
    float* Hb  = ws + (size_t)NN * 512;        // 8192*512 f32
    float* tb_ = ws + (size_t)2 * NN * 512;    // 8192
    float* rb_ = tb_ + NN;                     // 8192
    float* db_ = rb_ + NN;                     // 8192

    run_layer(X,  1024, 512, W1w, W1b, t1w, t1b, r1w, r1b, A, Zb, tb_, rb_, db_, Hb,  stream);
    run_layer(Hb,  512, 256, W2w, W2b, t2w, t2b, r2w, r2b, A, Zb, tb_, rb_, db_, Hb,  stream);
    run_layer(Hb,  256,  64, W3w, W3b, t3w, t3b, r3w, r3b, A, Zb, tb_, rb_, db_, out, stream);
}

// Round 2
// 1497.595 us; speedup vs baseline: 2.4101x; 2.4101x over previous
//
#include <hip/hip_runtime.h>
#include <math.h>

#define NN 8192

typedef __attribute__((ext_vector_type(8))) short short8;
typedef __attribute__((ext_vector_type(4))) float f32x4;

__device__ __forceinline__ float bf2f(unsigned short u) {
    unsigned int x = ((unsigned int)u) << 16;
    return __builtin_bit_cast(float, x);
}
__device__ __forceinline__ unsigned short f2bf(float f) {
    unsigned int x = __builtin_bit_cast(unsigned int, f);
    x = x + 0x7FFFu + ((x >> 16) & 1u);
    return (unsigned short)(x >> 16);
}
__device__ __forceinline__ float fast_sigexp(float x) {
    float s = __builtin_amdgcn_rcpf(1.0f + __expf(-x));
    return __expf(s);
}
__device__ __forceinline__ void gload16(const void* g, void* l) {
    __builtin_amdgcn_global_load_lds(
        (const __attribute__((address_space(1))) unsigned int*)g,
        (__attribute__((address_space(3))) unsigned int*)l, 16, 0, 0);
}

// ---------------- projection: Z = relu(H @ W^T + b) ----------------
// Writes Zt (bf16, transposed [O][NN]) and/or Zf (fp32 [N][O]).
__global__ __launch_bounds__(256) void proj_gemm(
    const float* __restrict__ H, const float* __restrict__ W,
    const float* __restrict__ bias,
    unsigned short* __restrict__ Zt, float* __restrict__ Zf,
    int K, int O)
{
    __shared__ float Hs[64][17];
    __shared__ float Ws[64][17];
    const int tid = threadIdx.x;
    const int i0 = blockIdx.y * 64;
    const int o0 = blockIdx.x * 64;
    const int tx = tid & 15;        // o micro
    const int ty = tid >> 4;        // i micro
    const int lr = tid >> 2;        // load row 0..63
    const int lc = (tid & 3) << 2;  // load col 0,4,8,12
    const float* Hp = H + (size_t)(i0 + lr) * K + lc;
    const float* Wp = W + (size_t)(o0 + lr) * K + lc;
    float acc[4][4] = {};
    for (int k0 = 0; k0 < K; k0 += 16) {
        float4 h4 = *(const float4*)(Hp + k0);
        float4 w4 = *(const float4*)(Wp + k0);
        Hs[lr][lc+0] = h4.x; Hs[lr][lc+1] = h4.y; Hs[lr][lc+2] = h4.z; Hs[lr][lc+3] = h4.w;
        Ws[lr][lc+0] = w4.x; Ws[lr][lc+1] = w4.y; Ws[lr][lc+2] = w4.z; Ws[lr][lc+3] = w4.w;
        __syncthreads();
        #pragma unroll
        for (int k = 0; k < 16; ++k) {
            float a[4], b[4];
            #pragma unroll
            for (int u = 0; u < 4; ++u) a[u] = Hs[ty*4+u][k];
            #pragma unroll
            for (int v = 0; v < 4; ++v) b[v] = Ws[tx*4+v][k];
            #pragma unroll
            for (int u = 0; u < 4; ++u)
                #pragma unroll
                for (int v = 0; v < 4; ++v)
                    acc[u][v] = fmaf(a[u], b[v], acc[u][v]);
        }
        __syncthreads();
    }
    float o[4][4];
    #pragma unroll
    for (int u = 0; u < 4; ++u)
        #pragma unroll
        for (int v = 0; v < 4; ++v)
            o[u][v] = fmaxf(acc[u][v] + bias[o0 + tx*4 + v], 0.f);
    if (Zf) {
        #pragma unroll
        for (int u = 0; u < 4; ++u) {
            float4 o4 = {o[u][0], o[u][1], o[u][2], o[u][3]};
            *(float4*)(Zf + (size_t)(i0 + ty*4 + u) * O + o0 + tx*4) = o4;
        }
    }
    if (Zt) {
        #pragma unroll
        for (int v = 0; v < 4; ++v) {
            ushort4 h;
            h.x = f2bf(o[0][v]); h.y = f2bf(o[1][v]);
            h.z = f2bf(o[2][v]); h.w = f2bf(o[3][v]);
            *(ushort4*)(Zt + (size_t)(o0 + tx*4 + v) * NN + i0 + ty*4) = h;
        }
    }
}

// ---------------- t,r from transposed bf16 Z ----------------
__global__ __launch_bounds__(256) void tr_zt(
    const unsigned short* __restrict__ Zt,
    const float* __restrict__ tw, const float* __restrict__ tb,
    const float* __restrict__ rw, const float* __restrict__ rb,
    float* __restrict__ t, float* __restrict__ r, int O)
{
    const int i = blockIdx.x * 256 + threadIdx.x;
    float at = 0.f, ar = 0.f;
    for (int c = 0; c < O; c += 4) {
        #pragma unroll
        for (int cc = 0; cc < 4; ++cc) {
            float z = bf2f(Zt[(size_t)(c + cc) * NN + i]);
            at = fmaf(z, tw[c + cc], at);
            ar = fmaf(z, rw[c + cc], ar);
        }
    }
    t[i] = at + tb[0];
    r[i] = ar + rb[0];
}

// ---------------- P materialization + denom (bf16 P, fp32 atomic denom) ----------------
__global__ __launch_bounds__(256) void pmat(
    const float* __restrict__ A, const float* __restrict__ t,
    const float* __restrict__ r, unsigned short* __restrict__ P,
    float* __restrict__ denom)
{
    __shared__ float Aji[64][69];   // pad 69: conflict-free transposed reads
    __shared__ float ts[64];
    const int tid = threadIdx.x;
    const int i0 = blockIdx.y * 64;
    const int j0 = blockIdx.x * 64;
    const int lr = tid >> 2;
    const int lc = (tid & 3) << 4;
    {
        const float* src = A + (size_t)(j0 + lr) * NN + i0 + lc;
        float4 v0 = *(const float4*)(src + 0);
        float4 v1 = *(const float4*)(src + 4);
        float4 v2 = *(const float4*)(src + 8);
        float4 v3 = *(const float4*)(src + 12);
        float* d = &Aji[lr][lc];
        d[0]=v0.x; d[1]=v0.y; d[2]=v0.z; d[3]=v0.w;
        d[4]=v1.x; d[5]=v1.y; d[6]=v1.z; d[7]=v1.w;
        d[8]=v2.x; d[9]=v2.y; d[10]=v2.z; d[11]=v2.w;
        d[12]=v3.x; d[13]=v3.y; d[14]=v3.z; d[15]=v3.w;
    }
    if (tid < 64) ts[tid] = t[j0 + tid];
    const int i  = tid >> 2;
    const int jb = (tid & 3) << 4;
    const float ri = r[i0 + i];
    __syncthreads();
    const float* arow = A + (size_t)(i0 + i) * NN + j0 + jb;
    float rsum = 0.f;
    unsigned int w[8];
    #pragma unroll
    for (int q = 0; q < 4; ++q) {
        float4 a4 = *(const float4*)(arow + q*4);
        float av[4] = {a4.x, a4.y, a4.z, a4.w};
        unsigned short us[4];
        #pragma unroll
        for (int e = 0; e < 4; ++e) {
            int j = jb + q*4 + e;
            float x = fmaf(av[e], ts[j], Aji[j][i] * ri);
            float p = fast_sigexp(x);
            rsum += p;
            us[e] = f2bf(p);
        }
        w[q*2+0] = (unsigned int)us[0] | ((unsigned int)us[1] << 16);
        w[q*2+1] = (unsigned int)us[2] | ((unsigned int)us[3] << 16);
    }
    unsigned short* pd = P + (size_t)(i0 + i) * NN + j0 + jb;
    uint4 s0 = {w[0], w[1], w[2], w[3]};
    uint4 s1 = {w[4], w[5], w[6], w[7]};
    *(uint4*)(pd + 0) = s0;
    *(uint4*)(pd + 8) = s1;
    rsum += __shfl_xor(rsum, 1);
    rsum += __shfl_xor(rsum, 2);
    if ((tid & 3) == 0) atomicAdd(denom + i0 + i, rsum);
}

// ---------------- attention GEMM: bf16 MFMA, m97 structure ----------------
// out[i,c] = (1/denom[i]) * sum_j P[i,j] * Zt[c,j]   (both operands k-contiguous)
template<int BN, int WROWS, int WCOLS, bool ATOMIC>
__global__ __launch_bounds__(256) void attn_mfma(
    const unsigned short* __restrict__ P,    // [NN][NN] bf16
    const unsigned short* __restrict__ Zt,   // [O][NN] bf16
    const float* __restrict__ denom,
    float* __restrict__ Hout, int O, int kcount)
{
    constexpr int BM = 128, BK = 32;
    constexpr int MT = BM / (16 * WROWS);
    constexpr int NT = BN / (16 * WCOLS);
    constexpr int NA = (BM * BK * 2) / 4096;   // gload16 calls for A per thread
    constexpr int NB = (BN * BK * 2) / 4096;
    __shared__ unsigned short As[BM * BK];
    __shared__ unsigned short Bs[BN * BK];
    const int tid  = threadIdx.x;
    const int w    = tid >> 6;
    const int lane = tid & 63;
    const int quad = lane >> 4;
    const int m16  = lane & 15;
    const int i0 = blockIdx.y * BM;
    const int c0 = blockIdx.x * BN;
    const int wm = w % WROWS;
    const int wn = w / WROWS;
    const int kstart = blockIdx.z * kcount;

    const char* gpa[NA]; void* lpa[NA];
    #pragma unroll
    for (int n = 0; n < NA; ++n) {
        int o16 = n * 256 + w * 64 + lane;
        int row = o16 >> 2, ch = o16 & 3;
        int sc = ch ^ ((row >> 1) & 3);
        gpa[n] = (const char*)P + ((size_t)(i0 + row) * NN + (size_t)kstart * BK) * 2 + sc * 16;
        lpa[n] = (char*)As + n * 4096 + w * 1024 + lane * 16;
    }
    const char* gpb[NB]; void* lpb[NB];
    #pragma unroll
    for (int n = 0; n < NB; ++n) {
        int o16 = n * 256 + w * 64 + lane;
        int row = o16 >> 2, ch = o16 & 3;
        int sc = ch ^ ((row >> 1) & 3);
        gpb[n] = (const char*)Zt + ((size_t)(c0 + row) * NN + (size_t)kstart * BK) * 2 + sc * 16;
        lpb[n] = (char*)Bs + n * 4096 + w * 1024 + lane * 16;
    }

    int aoff[MT], boff[NT];
    #pragma unroll
    for (int mt = 0; mt < MT; ++mt) {
        int row = wm * (16 * MT) + mt * 16 + m16;
        int sc = quad ^ ((row >> 1) & 3);
        aoff[mt] = row * 32 + sc * 8;
    }
    #pragma unroll
    for (int nt = 0; nt < NT; ++nt) {
        int row = wn * (16 * NT) + nt * 16 + m16;
        int sc = quad ^ ((row >> 1) & 3);
        boff[nt] = row * 32 + sc * 8;
    }

    f32x4 acc[MT][NT];
    #pragma unroll
    for (int mt = 0; mt < MT; ++mt)
        #pragma unroll
        for (int nt = 0; nt < NT; ++nt)
            acc[mt][nt] = (f32x4){0.f, 0.f, 0.f, 0.f};

    for (int kk = 0; kk < kcount; ++kk) {
        #pragma unroll
        for (int n = 0; n < NA; ++n) { gload16(gpa[n], lpa[n]); gpa[n] += 64; }
        #pragma unroll
        for (int n = 0; n < NB; ++n) { gload16(gpb[n], lpb[n]); gpb[n] += 64; }
        __syncthreads();
        short8 af[MT], bf_[NT];
        #pragma unroll
        for (int mt = 0; mt < MT; ++mt) af[mt] = *(const short8*)(As + aoff[mt]);
        #pragma unroll
        for (int nt = 0; nt < NT; ++nt) bf_[nt] = *(const short8*)(Bs + boff[nt]);
        #pragma unroll
        for (int mt = 0; mt < MT; ++mt)
            #pragma unroll
            for (int nt = 0; nt < NT; ++nt)
                acc[mt][nt] = __builtin_amdgcn_mfma_f32_16x16x32_bf16(
                    af[mt], bf_[nt], acc[mt][nt], 0, 0, 0);
        __syncthreads();
    }

    const int colb = c0 + wn * (16 * NT) + m16;
    #pragma unroll
    for (int mt = 0; mt < MT; ++mt) {
        int rowb = i0 + wm * (16 * MT) + mt * 16 + quad * 4;
        float4 dv = *(const float4*)(denom + rowb);
        float dvv[4] = {dv.x, dv.y, dv.z, dv.w};
        #pragma unroll
        for (int rg = 0; rg < 4; ++rg) {
            float inv = __builtin_amdgcn_rcpf(dvv[rg]);
            float* orow = Hout + (size_t)(rowb + rg) * O + colb;
            #pragma unroll
            for (int nt = 0; nt < NT; ++nt) {
                float v = acc[mt][nt][rg] * inv;
                if (ATOMIC) atomicAdd(orow + nt * 16, v);
                else        orow[nt * 16] = v;
            }
        }
    }
}

// ================= fallback fp32 path (round-1 kernels) =================
__global__ __launch_bounds__(256) void tr_kernel(
    const float* __restrict__ Z,
    const float* __restrict__ tw, const float* __restrict__ tb,
    const float* __restrict__ rw, const float* __restrict__ rb,
    float* __restrict__ t, float* __restrict__ r, int O)
{
    const int wave = threadIdx.x >> 6;
    const int lane = threadIdx.x & 63;
    const int row  = blockIdx.x * 4 + wave;
    const float* z = Z + (size_t)row * O;
    float at = 0.f, ar = 0.f;
    for (int c = lane; c < O; c += 64) {
        float zv = z[c];
        at = fmaf(zv, tw[c], at);
        ar = fmaf(zv, rw[c], ar);
    }
    #pragma unroll
    for (int off = 32; off; off >>= 1) {
        at += __shfl_down(at, off);
        ar += __shfl_down(ar, off);
    }
    if (lane == 0) { t[row] = at + tb[0]; r[row] = ar + rb[0]; }
}

__global__ __launch_bounds__(256) void denom_kernel(
    const float* __restrict__ A, const float* __restrict__ t,
    const float* __restrict__ r, float* __restrict__ denom)
{
    __shared__ float Aij[64][65];
    __shared__ float Aji[64][65];
    __shared__ float ts[64];
    __shared__ float red[4][64];
    const int tid = threadIdx.x;
    const int i0 = blockIdx.x * 64;
    const int li = tid & 63;
    const int jq = tid >> 6;
    const int lr = tid >> 4;
    const int lc = (tid & 15) << 2;
    const float ri = r[i0 + li];
    float acc = 0.f;
    for (int j0 = 0; j0 < NN; j0 += 64) {
        if (tid < 64) ts[tid] = t[j0 + tid];
        #pragma unroll
        for (int rep = 0; rep < 4; ++rep) {
            int row = rep*16 + lr;
            float4 a4 = *(const float4*)(A + (size_t)(i0 + row) * NN + j0 + lc);
            Aij[row][lc+0] = a4.x; Aij[row][lc+1] = a4.y; Aij[row][lc+2] = a4.z; Aij[row][lc+3] = a4.w;
            float4 b4 = *(const float4*)(A + (size_t)(j0 + row) * NN + i0 + lc);
            Aji[row][lc+0] = b4.x; Aji[row][lc+1] = b4.y; Aji[row][lc+2] = b4.z; Aji[row][lc+3] = b4.w;
        }
        __syncthreads();
        #pragma unroll
        for (int jj = 0; jj < 16; ++jj) {
            int j = jq*16 + jj;
            float x = fmaf(Aij[li][j], ts[j], Aji[j][li] * ri);
            acc += fast_sigexp(x);
        }
        __syncthreads();
    }
    red[jq][li] = acc;
    __syncthreads();
    if (tid < 64)
        denom[i0 + tid] = red[0][tid] + red[1][tid] + red[2][tid] + red[3][tid];
}

__global__ __launch_bounds__(256) void attn_gemm(
    const float* __restrict__ A, const float* __restrict__ Z,
    const float* __restrict__ t, const float* __restrict__ r,
    const float* __restrict__ denom, float* __restrict__ Hout, int O)
{
    __shared__ float Pt[64][68];
    __shared__ float Zs[64][68];
    __shared__ float Ajs[64][65];
    __shared__ float ts[64];
    __shared__ float rs[64];
    const int tid = threadIdx.x;
    const int i0 = blockIdx.y * 64;
    const int c0 = blockIdx.x * 64;
    const int tx = tid & 15;
    const int ty = tid >> 4;
    const int lr = tid >> 4;
    const int lc = (tid & 15) << 2;
    if (tid < 64) rs[tid] = r[i0 + tid];
    float acc[4][4] = {};
    for (int j0 = 0; j0 < NN; j0 += 64) {
        if (tid < 64) ts[tid] = t[j0 + tid];
        #pragma unroll
        for (int rep = 0; rep < 4; ++rep) {
            int row = rep*16 + lr;
            float4 a4 = *(const float4*)(A + (size_t)(j0 + row) * NN + i0 + lc);
            Ajs[row][lc+0] = a4.x; Ajs[row][lc+1] = a4.y; Ajs[row][lc+2] = a4.z; Ajs[row][lc+3] = a4.w;
            float4 z4 = *(const float4*)(Z + (size_t)(j0 + row) * O + c0 + lc);
            *(float4*)&Zs[row][lc] = z4;
        }
        __syncthreads();
        #pragma unroll
        for (int rep = 0; rep < 4; ++rep) {
            int i = rep*16 + lr;
            float ri = rs[i];
            float4 a4 = *(const float4*)(A + (size_t)(i0 + i) * NN + j0 + lc);
            Pt[lc+0][i] = fast_sigexp(fmaf(a4.x, ts[lc+0], Ajs[lc+0][i] * ri));
            Pt[lc+1][i] = fast_sigexp(fmaf(a4.y, ts[lc+1], Ajs[lc+1][i] * ri));
            Pt[lc+2][i] = fast_sigexp(fmaf(a4.z, ts[lc+2], Ajs[lc+2][i] * ri));
            Pt[lc+3][i] = fast_sigexp(fmaf(a4.w, ts[lc+3], Ajs[lc+3][i] * ri));
        }
        __syncthreads();
        #pragma unroll
        for (int j = 0; j < 64; ++j) {
            float4 p4 = *(const float4*)&Pt[j][ty*4];
            float4 z4 = *(const float4*)&Zs[j][tx*4];
            float av[4] = {p4.x, p4.y, p4.z, p4.w};
            float bv[4] = {z4.x, z4.y, z4.z, z4.w};
            #pragma unroll
            for (int u = 0; u < 4; ++u)
                #pragma unroll
                for (int v = 0; v < 4; ++v)
                    acc[u][v] = fmaf(av[u], bv[v], acc[u][v]);
        }
        __syncthreads();
    }
    #pragma unroll
    for (int u = 0; u < 4; ++u) {
        int i = i0 + ty*4 + u;
        float inv = __builtin_amdgcn_rcpf(denom[i]);
        float4 o4;
        o4.x = acc[u][0] * inv;
        o4.y = acc[u][1] * inv;
        o4.z = acc[u][2] * inv;
        o4.w = acc[u][3] * inv;
        *(float4*)(Hout + (size_t)i * O + c0 + tx*4) = o4;
    }
}

// ---------------- host-side ----------------
extern "C" void kernel_launch(void* const* d_in, const int* in_sizes, int n_in,
                              void* d_out, int out_size, void* d_ws, size_t ws_size,
                              hipStream_t stream)
{
    (void)in_sizes; (void)n_in; (void)out_size;
    const float* X   = (const float*)d_in[0];
    const float* A   = (const float*)d_in[1];
    const float* Wws[3] = {(const float*)d_in[2],  (const float*)d_in[8],  (const float*)d_in[14]};
    const float* Wbs[3] = {(const float*)d_in[3],  (const float*)d_in[9],  (const float*)d_in[15]};
    const float* tws[3] = {(const float*)d_in[4],  (const float*)d_in[10], (const float*)d_in[16]};
    const float* tbs[3] = {(const float*)d_in[5],  (const float*)d_in[11], (const float*)d_in[17]};
    const float* rws[3] = {(const float*)d_in[6],  (const float*)d_in[12], (const float*)d_in[18]};
    const float* rbs[3] = {(const float*)d_in[7],  (const float*)d_in[13], (const float*)d_in[19]};
    const int Ks[3] = {1024, 512, 256};
    const int Os[3] = {512, 256, 64};
    float* out = (float*)d_out;
    char* ws = (char*)d_ws;

    const size_t offH  = 0;                       // fp32 H buffer, 16 MB
    const size_t offZt = (size_t)16 << 20;        // bf16 Zt, 8 MB
    const size_t offT  = (size_t)24 << 20;
    const size_t offR  = offT + 32768;
    const size_t offD  = offR + 32768;
    const size_t offP  = (size_t)25 << 20;        // bf16 P, 128 MB
    const size_t need  = offP + (size_t)NN * NN * 2;

    if (ws_size >= need) {
        float* Hb = (float*)(ws + offH);
        unsigned short* Zt = (unsigned short*)(ws + offZt);
        float* tv = (float*)(ws + offT);
        float* rv = (float*)(ws + offR);
        float* dv = (float*)(ws + offD);
        unsigned short* P = (unsigned short*)(ws + offP);
        const float* Hin = X;
        for (int L = 0; L < 3; ++L) {
            int K = Ks[L], O = Os[L];
            float* Hout = (L == 2) ? out : Hb;
            proj_gemm<<<dim3(O/64, NN/64), 256, 0, stream>>>(
                Hin, Wws[L], Wbs[L], Zt, nullptr, K, O);
            tr_zt<<<NN/256, 256, 0, stream>>>(Zt, tws[L], tbs[L], rws[L], rbs[L], tv, rv, O);
            hipMemsetAsync(dv, 0, NN * sizeof(float), stream);
            pmat<<<dim3(NN/64, NN/64), 256, 0, stream>>>(A, tv, rv, P, dv);
            if (O >= 128) {
                attn_mfma<128, 2, 2, false><<<dim3(O/128, NN/128), 256, 0, stream>>>(
                    P, Zt, dv, Hout, O, 256);
            } else {
                hipMemsetAsync(Hout, 0, (size_t)NN * O * sizeof(float), stream);
                attn_mfma<64, 4, 1, true><<<dim3(1, NN/128, 4), 256, 0, stream>>>(
                    P, Zt, dv, Hout, O, 64);
            }
            Hin = Hout;
        }
    } else {
        // fallback fp32 path (round-1)
        float* Zb  = (float*)ws;
        float* Hb  = (float*)(ws + ((size_t)16 << 20));
        float* tv  = (float*)(ws + ((size_t)32 << 20));
        float* rv  = tv + NN;
        float* dvv = rv + NN;
        const float* Hin = X;
        for (int L = 0; L < 3; ++L) {
            int K = Ks[L], O = Os[L];
            float* Hout = (L == 2) ? out : Hb;
            proj_gemm<<<dim3(O/64, NN/64), 256, 0, stream>>>(
                Hin, Wws[L], Wbs[L], nullptr, Zb, K, O);
            tr_kernel<<<NN/4, 256, 0, stream>>>(Zb, tws[L], tbs[L], rws[L], rbs[L], tv, rv, O);
            denom_kernel<<<NN/64, 256, 0, stream>>>(A, tv, rv, dvv);
            attn_gemm<<<dim3(O/64, NN/64), 256, 0, stream>>>(A, Zb, tv, rv, dvv, Hout, O);
            Hin = Hout;
        }
    }
}

// Round 3
// 1124.657 us; speedup vs baseline: 3.2093x; 1.3316x over previous
//
#include <hip/hip_runtime.h>
#include <math.h>

#define NN 8192

typedef __attribute__((ext_vector_type(8))) short short8;
typedef __attribute__((ext_vector_type(4))) float f32x4;

__device__ __forceinline__ float bf2f(unsigned short u) {
    unsigned int x = ((unsigned int)u) << 16;
    return __builtin_bit_cast(float, x);
}
__device__ __forceinline__ unsigned short f2bf(float f) {
    unsigned int x = __builtin_bit_cast(unsigned int, f);
    x = x + 0x7FFFu + ((x >> 16) & 1u);
    return (unsigned short)(x >> 16);
}
__device__ __forceinline__ float fast_sigexp(float x) {
    float s = __builtin_amdgcn_rcpf(1.0f + __expf(-x));
    return __expf(s);
}
__device__ __forceinline__ void gload16(const void* g, void* l) {
    __builtin_amdgcn_global_load_lds(
        (const __attribute__((address_space(1))) unsigned int*)g,
        (__attribute__((address_space(3))) unsigned int*)l, 16, 0, 0);
}

// ---------------- generic fp32 -> bf16 conversion (8 elems/thread) ----------------
__global__ __launch_bounds__(256) void cvt_bf16(
    const float* __restrict__ src, unsigned short* __restrict__ dst)
{
    size_t idx = ((size_t)blockIdx.x * 256 + threadIdx.x) * 8;
    float4 a = *(const float4*)(src + idx);
    float4 b = *(const float4*)(src + idx + 4);
    unsigned int w0 = (unsigned int)f2bf(a.x) | ((unsigned int)f2bf(a.y) << 16);
    unsigned int w1 = (unsigned int)f2bf(a.z) | ((unsigned int)f2bf(a.w) << 16);
    unsigned int w2 = (unsigned int)f2bf(b.x) | ((unsigned int)f2bf(b.y) << 16);
    unsigned int w3 = (unsigned int)f2bf(b.z) | ((unsigned int)f2bf(b.w) << 16);
    uint4 o = {w0, w1, w2, w3};
    *(uint4*)(dst + idx) = o;
}

// ---------------- projection GEMM (bf16 MFMA): Zt[o][i] = relu(H@W^T + b) ----------------
// Hbf: [NN][K] bf16, Wbf: [O][K] bf16. BM=128 (i), BN=64 (o), BK=32, 4 waves 2x2.
__global__ __launch_bounds__(256) void proj_mfma(
    const unsigned short* __restrict__ Hbf,
    const unsigned short* __restrict__ Wbf,
    const float* __restrict__ bias,
    unsigned short* __restrict__ Zt,
    int K, int O)
{
    constexpr int MT = 4, NT = 2;   // WROWS=2, WCOLS=2
    __shared__ unsigned short smem[8704];  // K-loop: As 4096 + Bs 2048; epilogue: 64x136
    unsigned short* As = smem;
    unsigned short* Bs = smem + 4096;
    const int tid = threadIdx.x;
    const int w = tid >> 6;
    const int lane = tid & 63;
    const int quad = lane >> 4;
    const int m16 = lane & 15;
    const int i0 = blockIdx.y * 128;
    const int o0 = blockIdx.x * 64;
    const int wm = w & 1;
    const int wn = w >> 1;

    const char* gpa[2]; void* lpa[2];
    #pragma unroll
    for (int n = 0; n < 2; ++n) {
        int o16 = n * 256 + w * 64 + lane;
        int row = o16 >> 2, ch = o16 & 3;
        int sc = ch ^ ((row >> 1) & 3);
        gpa[n] = (const char*)(Hbf + (size_t)(i0 + row) * K) + sc * 16;
        lpa[n] = (char*)As + n * 4096 + w * 1024 + lane * 16;
    }
    const char* gpb; void* lpb;
    {
        int o16 = w * 64 + lane;
        int row = o16 >> 2, ch = o16 & 3;
        int sc = ch ^ ((row >> 1) & 3);
        gpb = (const char*)(Wbf + (size_t)(o0 + row) * K) + sc * 16;
        lpb = (char*)Bs + w * 1024 + lane * 16;
    }
    int aoff[MT], boff[NT];
    #pragma unroll
    for (int mt = 0; mt < MT; ++mt) {
        int row = wm * 64 + mt * 16 + m16;
        int sc = quad ^ ((row >> 1) & 3);
        aoff[mt] = row * 32 + sc * 8;
    }
    #pragma unroll
    for (int nt = 0; nt < NT; ++nt) {
        int row = wn * 32 + nt * 16 + m16;
        int sc = quad ^ ((row >> 1) & 3);
        boff[nt] = row * 32 + sc * 8;
    }
    f32x4 acc[MT][NT];
    #pragma unroll
    for (int mt = 0; mt < MT; ++mt)
        #pragma unroll
        for (int nt = 0; nt < NT; ++nt)
            acc[mt][nt] = (f32x4){0.f, 0.f, 0.f, 0.f};

    for (int k0 = 0; k0 < K; k0 += 32) {
        gload16(gpa[0], lpa[0]); gpa[0] += 64;
        gload16(gpa[1], lpa[1]); gpa[1] += 64;
        gload16(gpb, lpb); gpb += 64;
        __syncthreads();
        short8 af[MT], bf_[NT];
        #pragma unroll
        for (int mt = 0; mt < MT; ++mt) af[mt] = *(const short8*)(As + aoff[mt]);
        #pragma unroll
        for (int nt = 0; nt < NT; ++nt) bf_[nt] = *(const short8*)(Bs + boff[nt]);
        #pragma unroll
        for (int mt = 0; mt < MT; ++mt)
            #pragma unroll
            for (int nt = 0; nt < NT; ++nt)
                acc[mt][nt] = __builtin_amdgcn_mfma_f32_16x16x32_bf16(
                    af[mt], bf_[nt], acc[mt][nt], 0, 0, 0);
        __syncthreads();
    }
    // epilogue: relu(+bias), transpose via LDS, coalesced bf16 store to Zt[o][i]
    #pragma unroll
    for (int nt = 0; nt < NT; ++nt) {
        int ol = wn * 32 + nt * 16 + m16;
        float bv = bias[o0 + ol];
        #pragma unroll
        for (int mt = 0; mt < MT; ++mt)
            #pragma unroll
            for (int rg = 0; rg < 4; ++rg) {
                int il = wm * 64 + mt * 16 + quad * 4 + rg;
                smem[ol * 136 + il] = f2bf(fmaxf(acc[mt][nt][rg] + bv, 0.f));
            }
    }
    __syncthreads();
    #pragma unroll
    for (int c = 0; c < 4; ++c) {
        int cc = c * 256 + tid;
        int ol = cc >> 4;
        int ic = (cc & 15) << 3;
        *(uint4*)(Zt + (size_t)(o0 + ol) * NN + i0 + ic) = *(const uint4*)&smem[ol * 136 + ic];
    }
}

// ---------------- t,r: column-split atomic dots over Zt ----------------
__global__ __launch_bounds__(256) void tr_zt(
    const unsigned short* __restrict__ Zt,
    const float* __restrict__ tw, const float* __restrict__ tb,
    const float* __restrict__ rw, const float* __restrict__ rb,
    float* __restrict__ t, float* __restrict__ r)
{
    const int i  = blockIdx.x * 256 + threadIdx.x;
    const int c0 = blockIdx.y * 64;
    float at = 0.f, ar = 0.f;
    for (int c = c0; c < c0 + 64; ++c) {
        float z = bf2f(Zt[(size_t)c * NN + i]);
        at = fmaf(z, tw[c], at);
        ar = fmaf(z, rw[c], ar);
    }
    if (blockIdx.y == 0) { at += tb[0]; ar += rb[0]; }
    atomicAdd(t + i, at);
    atomicAdd(r + i, ar);
}

// ---------------- P band materialization + denom ----------------
template<typename AT> struct ALoad;
template<> struct ALoad<float> {
    static __device__ __forceinline__ void ld16(const float* p, float* d) {
        float4 v0 = ((const float4*)p)[0];
        float4 v1 = ((const float4*)p)[1];
        float4 v2 = ((const float4*)p)[2];
        float4 v3 = ((const float4*)p)[3];
        d[0]=v0.x; d[1]=v0.y; d[2]=v0.z; d[3]=v0.w;
        d[4]=v1.x; d[5]=v1.y; d[6]=v1.z; d[7]=v1.w;
        d[8]=v2.x; d[9]=v2.y; d[10]=v2.z; d[11]=v2.w;
        d[12]=v3.x; d[13]=v3.y; d[14]=v3.z; d[15]=v3.w;
    }
};
template<> struct ALoad<unsigned short> {
    static __device__ __forceinline__ void ld16(const unsigned short* p, float* d) {
        uint4 u0 = ((const uint4*)p)[0];
        uint4 u1 = ((const uint4*)p)[1];
        unsigned int wd[8] = {u0.x, u0.y, u0.z, u0.w, u1.x, u1.y, u1.z, u1.w};
        #pragma unroll
        for (int k = 0; k < 8; ++k) {
            d[2*k]   = __builtin_bit_cast(float, wd[k] << 16);
            d[2*k+1] = __builtin_bit_cast(float, wd[k] & 0xFFFF0000u);
        }
    }
};

template<typename AT>
__global__ __launch_bounds__(256) void pmat_t(
    const AT* __restrict__ A, const float* __restrict__ t,
    const float* __restrict__ r, unsigned short* __restrict__ Pb,
    float* __restrict__ denom, int i_base)
{
    __shared__ float Aji[64][69];
    __shared__ float ts[64];
    const int tid = threadIdx.x;
    const int iL0 = blockIdx.y * 64;
    const int iG0 = i_base + iL0;
    const int j0  = blockIdx.x * 64;
    const int lr = tid >> 2;
    const int lc = (tid & 3) << 4;
    ALoad<AT>::ld16(A + (size_t)(j0 + lr) * NN + iG0 + lc, &Aji[lr][lc]);
    if (tid < 64) ts[tid] = t[j0 + tid];
    const int i  = tid >> 2;
    const int jb = (tid & 3) << 4;
    const float ri = r[iG0 + i];
    __syncthreads();
    float av[16];
    ALoad<AT>::ld16(A + (size_t)(iG0 + i) * NN + j0 + jb, av);
    float rsum = 0.f;
    unsigned int wd[8];
    #pragma unroll
    for (int e = 0; e < 16; ++e) {
        int j = jb + e;
        float x = fmaf(av[e], ts[j], Aji[j][i] * ri);
        float p = fast_sigexp(x);
        rsum += p;
        if (e & 1) wd[e >> 1] |= ((unsigned int)f2bf(p)) << 16;
        else       wd[e >> 1]  = (unsigned int)f2bf(p);
    }
    unsigned short* pd = Pb + (size_t)(iL0 + i) * NN + j0 + jb;
    uint4 s0 = {wd[0], wd[1], wd[2], wd[3]};
    uint4 s1 = {wd[4], wd[5], wd[6], wd[7]};
    ((uint4*)pd)[0] = s0;
    ((uint4*)pd)[1] = s1;
    rsum += __shfl_xor(rsum, 1);
    rsum += __shfl_xor(rsum, 2);
    if ((tid & 3) == 0) atomicAdd(denom + iG0 + i, rsum);
}

// ---------------- attention GEMM: bf16 MFMA, K-split atomic accumulate ----------------
// out[i,c] += (1/denom[i]) * sum_{j in slice} P[i,j] * Zt[c,j]
template<int BM, int BN, int WROWS, int WCOLS>
__global__ __launch_bounds__(256) void attn_mfma(
    const unsigned short* __restrict__ P,    // band rows, [*][NN] bf16
    const unsigned short* __restrict__ Zt,   // [O][NN] bf16
    const float* __restrict__ denom,
    float* __restrict__ Hout, int O, int kcount)
{
    constexpr int BK = 32;
    constexpr int MT = BM / (16 * WROWS);
    constexpr int NT = BN / (16 * WCOLS);
    constexpr int NA = (BM * BK * 2) / 4096;
    constexpr int NB = (BN * BK * 2) / 4096;
    __shared__ unsigned short As[BM * BK];
    __shared__ unsigned short Bs[BN * BK];
    const int tid  = threadIdx.x;
    const int w    = tid >> 6;
    const int lane = tid & 63;
    const int quad = lane >> 4;
    const int m16  = lane & 15;
    const int i0 = blockIdx.y * BM;
    const int c0 = blockIdx.x * BN;
    const int wm = w % WROWS;
    const int wn = w / WROWS;
    const int kstart = blockIdx.z * kcount;

    const char* gpa[NA]; void* lpa[NA];
    #pragma unroll
    for (int n = 0; n < NA; ++n) {
        int o16 = n * 256 + w * 64 + lane;
        int row = o16 >> 2, ch = o16 & 3;
        int sc = ch ^ ((row >> 1) & 3);
        gpa[n] = (const char*)P + ((size_t)(i0 + row) * NN + (size_t)kstart * BK) * 2 + sc * 16;
        lpa[n] = (char*)As + n * 4096 + w * 1024 + lane * 16;
    }
    const char* gpb[NB]; void* lpb[NB];
    #pragma unroll
    for (int n = 0; n < NB; ++n) {
        int o16 = n * 256 + w * 64 + lane;
        int row = o16 >> 2, ch = o16 & 3;
        int sc = ch ^ ((row >> 1) & 3);
        gpb[n] = (const char*)Zt + ((size_t)(c0 + row) * NN + (size_t)kstart * BK) * 2 + sc * 16;
        lpb[n] = (char*)Bs + n * 4096 + w * 1024 + lane * 16;
    }

    int aoff[MT], boff[NT];
    #pragma unroll
    for (int mt = 0; mt < MT; ++mt) {
        int row = wm * (16 * MT) + mt * 16 + m16;
        int sc = quad ^ ((row >> 1) & 3);
        aoff[mt] = row * 32 + sc * 8;
    }
    #pragma unroll
    for (int nt = 0; nt < NT; ++nt) {
        int row = wn * (16 * NT) + nt * 16 + m16;
        int sc = quad ^ ((row >> 1) & 3);
        boff[nt] = row * 32 + sc * 8;
    }

    f32x4 acc[MT][NT];
    #pragma unroll
    for (int mt = 0; mt < MT; ++mt)
        #pragma unroll
        for (int nt = 0; nt < NT; ++nt)
            acc[mt][nt] = (f32x4){0.f, 0.f, 0.f, 0.f};

    for (int kk = 0; kk < kcount; ++kk) {
        #pragma unroll
        for (int n = 0; n < NA; ++n) { gload16(gpa[n], lpa[n]); gpa[n] += 64; }
        #pragma unroll
        for (int n = 0; n < NB; ++n) { gload16(gpb[n], lpb[n]); gpb[n] += 64; }
        __syncthreads();
        short8 af[MT], bf_[NT];
        #pragma unroll
        for (int mt = 0; mt < MT; ++mt) af[mt] = *(const short8*)(As + aoff[mt]);
        #pragma unroll
        for (int nt = 0; nt < NT; ++nt) bf_[nt] = *(const short8*)(Bs + boff[nt]);
        #pragma unroll
        for (int mt = 0; mt < MT; ++mt)
            #pragma unroll
            for (int nt = 0; nt < NT; ++nt)
                acc[mt][nt] = __builtin_amdgcn_mfma_f32_16x16x32_bf16(
                    af[mt], bf_[nt], acc[mt][nt], 0, 0, 0);
        __syncthreads();
    }

    const int colb = c0 + wn * (16 * NT) + m16;
    #pragma unroll
    for (int mt = 0; mt < MT; ++mt) {
        int rowb = i0 + wm * (16 * MT) + mt * 16 + quad * 4;
        float4 dv = *(const float4*)(denom + rowb);
        float dvv[4] = {dv.x, dv.y, dv.z, dv.w};
        #pragma unroll
        for (int rg = 0; rg < 4; ++rg) {
            float inv = __builtin_amdgcn_rcpf(dvv[rg]);
            float* orow = Hout + (size_t)(rowb + rg) * O + colb;
            #pragma unroll
            for (int nt = 0; nt < NT; ++nt)
                atomicAdd(orow + nt * 16, acc[mt][nt][rg] * inv);
        }
    }
}

// ---------------- host ----------------
extern "C" void kernel_launch(void* const* d_in, const int* in_sizes, int n_in,
                              void* d_out, int out_size, void* d_ws, size_t ws_size,
                              hipStream_t stream)
{
    (void)in_sizes; (void)n_in; (void)out_size;
    const float* X = (const float*)d_in[0];
    const float* A = (const float*)d_in[1];
    const float* Wws[3] = {(const float*)d_in[2],  (const float*)d_in[8],  (const float*)d_in[14]};
    const float* Wbs[3] = {(const float*)d_in[3],  (const float*)d_in[9],  (const float*)d_in[15]};
    const float* tws[3] = {(const float*)d_in[4],  (const float*)d_in[10], (const float*)d_in[16]};
    const float* tbs[3] = {(const float*)d_in[5],  (const float*)d_in[11], (const float*)d_in[17]};
    const float* rws[3] = {(const float*)d_in[6],  (const float*)d_in[12], (const float*)d_in[18]};
    const float* rbs[3] = {(const float*)d_in[7],  (const float*)d_in[13], (const float*)d_in[19]};
    const int Ks[3] = {1024, 512, 256};
    const int Os[3] = {512, 256, 64};
    float* out = (float*)d_out;
    char* ws = (char*)d_ws;
    const size_t MB = (size_t)1 << 20;

    // layout: Pb 64MB | Zt 8MB | HbX 16MB (bf16-X then fp32 Hout) | Hbf2 8MB | Wbf 2MB | small | [Abf 128MB]
    unsigned short* Pb   = (unsigned short*)(ws);
    unsigned short* Zt   = (unsigned short*)(ws + 64 * MB);
    unsigned short* HbfX = (unsigned short*)(ws + 72 * MB);
    float*          Hb   = (float*)(ws + 72 * MB);          // aliases HbfX (time-disjoint)
    unsigned short* Hbf2 = (unsigned short*)(ws + 88 * MB);
    unsigned short* Wbf  = (unsigned short*)(ws + 96 * MB);
    float* tv = (float*)(ws + 98 * MB);
    float* rv = tv + NN;
    float* dv = rv + NN;
    unsigned short* Abf = (unsigned short*)(ws + 99 * MB);
    const bool useAbf = (ws_size >= 227 * MB);

    unsigned short* WbfL[3] = {Wbf, Wbf + 512 * 1024, Wbf + 512 * 1024 + 256 * 512};

    // one-time conversions
    cvt_bf16<<<(NN * 1024) / 2048, 256, 0, stream>>>(X, HbfX);
    for (int L = 0; L < 3; ++L)
        cvt_bf16<<<(Os[L] * Ks[L]) / 2048, 256, 0, stream>>>(Wws[L], WbfL[L]);
    if (useAbf)
        cvt_bf16<<<(int)(((size_t)NN * NN) / 2048), 256, 0, stream>>>(A, Abf);

    const unsigned short* Hbf_in = HbfX;
    for (int L = 0; L < 3; ++L) {
        int K = Ks[L], O = Os[L];
        float* Hout = (L == 2) ? out : Hb;
        proj_mfma<<<dim3(O / 64, NN / 128), 256, 0, stream>>>(
            Hbf_in, WbfL[L], Wbs[L], Zt, K, O);
        hipMemsetAsync(tv, 0, 96 * 1024, stream);
        tr_zt<<<dim3(NN / 256, O / 64), 256, 0, stream>>>(
            Zt, tws[L], tbs[L], rws[L], rbs[L], tv, rv);
        hipMemsetAsync(Hout, 0, (size_t)NN * O * sizeof(float), stream);
        for (int b = 0; b < 2; ++b) {
            int ib = b * 4096;
            if (useAbf)
                pmat_t<unsigned short><<<dim3(NN / 64, 64), 256, 0, stream>>>(
                    Abf, tv, rv, Pb, dv, ib);
            else
                pmat_t<float><<<dim3(NN / 64, 64), 256, 0, stream>>>(
                    A, tv, rv, Pb, dv, ib);
            float* Hob = Hout + (size_t)ib * O;
            const float* dvb = dv + ib;
            if (O == 512)
                attn_mfma<128, 128, 2, 2><<<dim3(4, 32, 8), 256, 0, stream>>>(
                    Pb, Zt, dvb, Hob, O, 32);
            else if (O == 256)
                attn_mfma<128, 128, 2, 2><<<dim3(2, 32, 16), 256, 0, stream>>>(
                    Pb, Zt, dvb, Hob, O, 16);
            else
                attn_mfma<64, 64, 2, 2><<<dim3(1, 64, 16), 256, 0, stream>>>(
                    Pb, Zt, dvb, Hob, O, 16);
        }
        if (L < 2) {
            cvt_bf16<<<(int)(((size_t)NN * O) / 2048), 256, 0, stream>>>(Hout, Hbf2);
            Hbf_in = Hbf2;
        }
    }
}

// Round 4
// 1002.080 us; speedup vs baseline: 3.6019x; 1.1223x over previous
//
#include <hip/hip_runtime.h>
#include <math.h>

#define NN 8192

typedef __attribute__((ext_vector_type(8))) short short8;
typedef __attribute__((ext_vector_type(4))) float f32x4;

__device__ __forceinline__ float bf2f(unsigned short u) {
    unsigned int x = ((unsigned int)u) << 16;
    return __builtin_bit_cast(float, x);
}
__device__ __forceinline__ unsigned short f2bf(float f) {
    unsigned int x = __builtin_bit_cast(unsigned int, f);
    x = x + 0x7FFFu + ((x >> 16) & 1u);
    return (unsigned short)(x >> 16);
}
__device__ __forceinline__ float fast_sigexp(float x) {
    float s = __builtin_amdgcn_rcpf(1.0f + __expf(-x));
    return __expf(s);
}
__device__ __forceinline__ void gload16(const void* g, void* l) {
    __builtin_amdgcn_global_load_lds(
        (const __attribute__((address_space(1))) unsigned int*)g,
        (__attribute__((address_space(3))) unsigned int*)l, 16, 0, 0);
}

// ---------------- fp32 -> bf16 conversion ----------------
__global__ __launch_bounds__(256) void cvt_bf16(
    const float* __restrict__ src, unsigned short* __restrict__ dst)
{
    size_t idx = ((size_t)blockIdx.x * 256 + threadIdx.x) * 8;
    float4 a = *(const float4*)(src + idx);
    float4 b = *(const float4*)(src + idx + 4);
    unsigned int w0 = (unsigned int)f2bf(a.x) | ((unsigned int)f2bf(a.y) << 16);
    unsigned int w1 = (unsigned int)f2bf(a.z) | ((unsigned int)f2bf(a.w) << 16);
    unsigned int w2 = (unsigned int)f2bf(b.x) | ((unsigned int)f2bf(b.y) << 16);
    unsigned int w3 = (unsigned int)f2bf(b.z) | ((unsigned int)f2bf(b.w) << 16);
    uint4 o = {w0, w1, w2, w3};
    *(uint4*)(dst + idx) = o;
}

// ---------------- load-16-as-float helpers ----------------
template<typename AT> struct ALoad;
template<> struct ALoad<float> {
    static __device__ __forceinline__ void ld16(const float* p, float* d) {
        float4 v0 = ((const float4*)p)[0];
        float4 v1 = ((const float4*)p)[1];
        float4 v2 = ((const float4*)p)[2];
        float4 v3 = ((const float4*)p)[3];
        d[0]=v0.x; d[1]=v0.y; d[2]=v0.z; d[3]=v0.w;
        d[4]=v1.x; d[5]=v1.y; d[6]=v1.z; d[7]=v1.w;
        d[8]=v2.x; d[9]=v2.y; d[10]=v2.z; d[11]=v2.w;
        d[12]=v3.x; d[13]=v3.y; d[14]=v3.z; d[15]=v3.w;
    }
};
template<> struct ALoad<unsigned short> {
    static __device__ __forceinline__ void ld16(const unsigned short* p, float* d) {
        uint4 u0 = ((const uint4*)p)[0];
        uint4 u1 = ((const uint4*)p)[1];
        unsigned int wd[8] = {u0.x, u0.y, u0.z, u0.w, u1.x, u1.y, u1.z, u1.w};
        #pragma unroll
        for (int k = 0; k < 8; ++k) {
            d[2*k]   = __builtin_bit_cast(float, wd[k] << 16);
            d[2*k+1] = __builtin_bit_cast(float, wd[k] & 0xFFFF0000u);
        }
    }
};
// stage 16 elems of A as bf16 into LDS (32 B)
template<typename AT> struct Stage16;
template<> struct Stage16<unsigned short> {
    static __device__ __forceinline__ void st(const unsigned short* g, unsigned short* l) {
        uint4 a = ((const uint4*)g)[0];
        uint4 b = ((const uint4*)g)[1];
        ((uint4*)l)[0] = a;
        ((uint4*)l)[1] = b;
    }
};
template<> struct Stage16<float> {
    static __device__ __forceinline__ void st(const float* g, unsigned short* l) {
        float v[16];
        ALoad<float>::ld16(g, v);
        unsigned int wd[8];
        #pragma unroll
        for (int k = 0; k < 8; ++k)
            wd[k] = (unsigned int)f2bf(v[2*k]) | ((unsigned int)f2bf(v[2*k+1]) << 16);
        uint4 s0 = {wd[0], wd[1], wd[2], wd[3]};
        uint4 s1 = {wd[4], wd[5], wd[6], wd[7]};
        ((uint4*)l)[0] = s0;
        ((uint4*)l)[1] = s1;
    }
};

// ---------------- projection GEMM (bf16 MFMA): Zt[o][i] = relu(H@W^T + b) ----------------
__global__ __launch_bounds__(256) void proj_mfma(
    const unsigned short* __restrict__ Hbf,
    const unsigned short* __restrict__ Wbf,
    const float* __restrict__ bias,
    unsigned short* __restrict__ Zt,
    int K, int O)
{
    constexpr int MT = 4, NT = 2;
    __shared__ unsigned short smem[8704];
    unsigned short* As = smem;
    unsigned short* Bs = smem + 4096;
    const int tid = threadIdx.x;
    const int w = tid >> 6;
    const int lane = tid & 63;
    const int quad = lane >> 4;
    const int m16 = lane & 15;
    const int i0 = blockIdx.y * 128;
    const int o0 = blockIdx.x * 64;
    const int wm = w & 1;
    const int wn = w >> 1;

    const char* gpa[2]; void* lpa[2];
    #pragma unroll
    for (int n = 0; n < 2; ++n) {
        int o16 = n * 256 + w * 64 + lane;
        int row = o16 >> 2, ch = o16 & 3;
        int sc = ch ^ ((row >> 1) & 3);
        gpa[n] = (const char*)(Hbf + (size_t)(i0 + row) * K) + sc * 16;
        lpa[n] = (char*)As + n * 4096 + w * 1024 + lane * 16;
    }
    const char* gpb; void* lpb;
    {
        int o16 = w * 64 + lane;
        int row = o16 >> 2, ch = o16 & 3;
        int sc = ch ^ ((row >> 1) & 3);
        gpb = (const char*)(Wbf + (size_t)(o0 + row) * K) + sc * 16;
        lpb = (char*)Bs + w * 1024 + lane * 16;
    }
    int aoff[MT], boff[NT];
    #pragma unroll
    for (int mt = 0; mt < MT; ++mt) {
        int row = wm * 64 + mt * 16 + m16;
        int sc = quad ^ ((row >> 1) & 3);
        aoff[mt] = row * 32 + sc * 8;
    }
    #pragma unroll
    for (int nt = 0; nt < NT; ++nt) {
        int row = wn * 32 + nt * 16 + m16;
        int sc = quad ^ ((row >> 1) & 3);
        boff[nt] = row * 32 + sc * 8;
    }
    f32x4 acc[MT][NT];
    #pragma unroll
    for (int mt = 0; mt < MT; ++mt)
        #pragma unroll
        for (int nt = 0; nt < NT; ++nt)
            acc[mt][nt] = (f32x4){0.f, 0.f, 0.f, 0.f};

    for (int k0 = 0; k0 < K; k0 += 32) {
        gload16(gpa[0], lpa[0]); gpa[0] += 64;
        gload16(gpa[1], lpa[1]); gpa[1] += 64;
        gload16(gpb, lpb); gpb += 64;
        __syncthreads();
        short8 af[MT], bf_[NT];
        #pragma unroll
        for (int mt = 0; mt < MT; ++mt) af[mt] = *(const short8*)(As + aoff[mt]);
        #pragma unroll
        for (int nt = 0; nt < NT; ++nt) bf_[nt] = *(const short8*)(Bs + boff[nt]);
        #pragma unroll
        for (int mt = 0; mt < MT; ++mt)
            #pragma unroll
            for (int nt = 0; nt < NT; ++nt)
                acc[mt][nt] = __builtin_amdgcn_mfma_f32_16x16x32_bf16(
                    af[mt], bf_[nt], acc[mt][nt], 0, 0, 0);
        __syncthreads();
    }
    #pragma unroll
    for (int nt = 0; nt < NT; ++nt) {
        int ol = wn * 32 + nt * 16 + m16;
        float bv = bias[o0 + ol];
        #pragma unroll
        for (int mt = 0; mt < MT; ++mt)
            #pragma unroll
            for (int rg = 0; rg < 4; ++rg) {
                int il = wm * 64 + mt * 16 + quad * 4 + rg;
                smem[ol * 136 + il] = f2bf(fmaxf(acc[mt][nt][rg] + bv, 0.f));
            }
    }
    __syncthreads();
    #pragma unroll
    for (int c = 0; c < 4; ++c) {
        int cc = c * 256 + tid;
        int ol = cc >> 4;
        int ic = (cc & 15) << 3;
        *(uint4*)(Zt + (size_t)(o0 + ol) * NN + i0 + ic) = *(const uint4*)&smem[ol * 136 + ic];
    }
}

// ---------------- t,r: column-split atomic dots over Zt ----------------
__global__ __launch_bounds__(256) void tr_zt(
    const unsigned short* __restrict__ Zt,
    const float* __restrict__ tw, const float* __restrict__ tb,
    const float* __restrict__ rw, const float* __restrict__ rb,
    float* __restrict__ t, float* __restrict__ r)
{
    const int i  = blockIdx.x * 256 + threadIdx.x;
    const int c0 = blockIdx.y * 64;
    float at = 0.f, ar = 0.f;
    for (int c = c0; c < c0 + 64; ++c) {
        float z = bf2f(Zt[(size_t)c * NN + i]);
        at = fmaf(z, tw[c], at);
        ar = fmaf(z, rw[c], ar);
    }
    if (blockIdx.y == 0) { at += tb[0]; ar += rb[0]; }
    atomicAdd(t + i, at);
    atomicAdd(r + i, ar);
}

// ---------------- fused attention: P on the fly + bf16 MFMA + denom ----------------
// Hacc[i,c] += sum_{j slice} p(i,j)*Z[c,j];  denom[i] += sum_j p(i,j) (x==0 only)
template<int BN, typename AT>
__global__ __launch_bounds__(256) void attn_fused(
    const AT* __restrict__ A,
    const unsigned short* __restrict__ Zt,   // [O][NN] bf16
    const float* __restrict__ t, const float* __restrict__ r,
    float* __restrict__ Hacc, float* __restrict__ denom,
    int O, int kcount)
{
    constexpr int BM = 128, BK = 32;
    constexpr int MT = 4;              // WROWS=2
    constexpr int NT = BN / 32;        // WCOLS=2
    constexpr int NB = (BN * BK * 2) / 4096;
    __shared__ unsigned short As[BM * BK];        // P tile, MFMA layout
    __shared__ unsigned short Bs[2][BN * BK];     // Zt tiles, double-buffered
    __shared__ unsigned short Ac[BK][136];        // A-col tile [j][i], padded
    const int tid  = threadIdx.x;
    const int w    = tid >> 6;
    const int lane = tid & 63;
    const int quad = lane >> 4;
    const int m16  = lane & 15;
    const int i0 = blockIdx.y * BM;
    const int c0 = blockIdx.x * BN;
    const int wm = w & 1;
    const int wn = w >> 1;
    const int jbase = blockIdx.z * kcount * BK;

    // compute-role: thread owns (row ci, 16-j half jh)
    const int ci = tid >> 1;
    const int jh = tid & 1;
    const float ri = r[i0 + ci];
    const int si = (ci >> 1) & 3;
    unsigned short* asw0 = As + ci * 32 + (((jh * 2)    ) ^ si) * 8;
    unsigned short* asw1 = As + ci * 32 + (((jh * 2) + 1) ^ si) * 8;
    // staging-role: thread stages A[j0+sj][i0 + sm*16 .. +16]
    const int sj = tid >> 3;
    const int sm = tid & 7;
    unsigned short* acw = &Ac[sj][sm * 16];

    // Bs gload pointers
    const char* gpb[NB]; unsigned int lob[NB];
    #pragma unroll
    for (int n = 0; n < NB; ++n) {
        int o16 = n * 256 + w * 64 + lane;
        int row = o16 >> 2, ch = o16 & 3;
        int sc = ch ^ ((row >> 1) & 3);
        gpb[n] = (const char*)Zt + ((size_t)(c0 + row) * NN + jbase) * 2 + sc * 16;
        lob[n] = n * 4096 + w * 1024 + lane * 16;
    }
    int aoff[MT], boff[NT];
    #pragma unroll
    for (int mt = 0; mt < MT; ++mt) {
        int row = wm * 64 + mt * 16 + m16;
        int sc = quad ^ ((row >> 1) & 3);
        aoff[mt] = row * 32 + sc * 8;
    }
    #pragma unroll
    for (int nt = 0; nt < NT; ++nt) {
        int row = wn * (BN / 2) + nt * 16 + m16;
        int sc = quad ^ ((row >> 1) & 3);
        boff[nt] = row * 32 + sc * 8;
    }

    f32x4 acc[MT][NT];
    #pragma unroll
    for (int mt = 0; mt < MT; ++mt)
        #pragma unroll
        for (int nt = 0; nt < NT; ++nt)
            acc[mt][nt] = (f32x4){0.f, 0.f, 0.f, 0.f};

    // prologue: Bs[0]
    #pragma unroll
    for (int n = 0; n < NB; ++n)
        gload16(gpb[n], (char*)Bs[0] + lob[n]);

    float rsum = 0.f;
    const AT* arow = A + (size_t)(i0 + ci) * NN + jbase + jh * 16;
    const float* tptr = t + jbase + jh * 16;

    for (int kk = 0; kk < kcount; ++kk) {
        const int j0 = jbase + kk * BK;
        // phase0: prefetch next Bs; stage A-col; issue reg loads
        if (kk + 1 < kcount) {
            #pragma unroll
            for (int n = 0; n < NB; ++n)
                gload16(gpb[n] + (size_t)(kk + 1) * 64, (char*)Bs[(kk + 1) & 1] + lob[n]);
        }
        Stage16<AT>::st(A + (size_t)(j0 + sj) * NN + i0 + sm * 16, acw);
        float av[16], tv[16];
        ALoad<AT>::ld16(arow + (size_t)kk * BK, av);
        ALoad<float>::ld16(tptr + kk * BK, tv);
        __syncthreads();                     // Ac ready (Bs[kk&1] also drained)
        // phase1: p = exp(sigmoid(a_ij*t_j + a_ji*r_i)), write into As
        unsigned int wd[8];
        #pragma unroll
        for (int e = 0; e < 16; ++e) {
            float aji = bf2f(Ac[jh * 16 + e][ci]);
            float x = fmaf(av[e], tv[e], aji * ri);
            float p = fast_sigexp(x);
            rsum += p;
            if (e & 1) wd[e >> 1] |= ((unsigned int)f2bf(p)) << 16;
            else       wd[e >> 1]  = (unsigned int)f2bf(p);
        }
        {
            uint4 s0 = {wd[0], wd[1], wd[2], wd[3]};
            uint4 s1 = {wd[4], wd[5], wd[6], wd[7]};
            *(uint4*)asw0 = s0;
            *(uint4*)asw1 = s1;
        }
        __syncthreads();                     // As ready
        // phase2: MFMA
        const unsigned short* bsb = Bs[kk & 1];
        short8 af[MT], bf_[NT];
        #pragma unroll
        for (int mt = 0; mt < MT; ++mt) af[mt] = *(const short8*)(As + aoff[mt]);
        #pragma unroll
        for (int nt = 0; nt < NT; ++nt) bf_[nt] = *(const short8*)(bsb + boff[nt]);
        #pragma unroll
        for (int mt = 0; mt < MT; ++mt)
            #pragma unroll
            for (int nt = 0; nt < NT; ++nt)
                acc[mt][nt] = __builtin_amdgcn_mfma_f32_16x16x32_bf16(
                    af[mt], bf_[nt], acc[mt][nt], 0, 0, 0);
        __syncthreads();                     // protect As/Ac before next overwrite
    }

    // denom accumulation (unquantized fp32 row sums), x==0 blocks only
    rsum += __shfl_xor(rsum, 1);
    if (jh == 0 && blockIdx.x == 0)
        atomicAdd(denom + i0 + ci, rsum);

    // unnormalized atomic output
    const int colb = c0 + wn * (BN / 2) + m16;
    #pragma unroll
    for (int mt = 0; mt < MT; ++mt) {
        int rowb = i0 + wm * 64 + mt * 16 + quad * 4;
        #pragma unroll
        for (int rg = 0; rg < 4; ++rg) {
            float* orow = Hacc + (size_t)(rowb + rg) * O + colb;
            #pragma unroll
            for (int nt = 0; nt < NT; ++nt)
                atomicAdd(orow + nt * 16, acc[mt][nt][rg]);
        }
    }
}

// ---------------- normalize + emit (f32 out or bf16 next-layer input) ----------------
__global__ __launch_bounds__(256) void norm_cvt(
    const float* __restrict__ Hacc, const float* __restrict__ denom,
    float* __restrict__ outf, unsigned short* __restrict__ outb, int O)
{
    const int gid = blockIdx.x * 256 + threadIdx.x;
    const int n4 = O >> 2;
    const int i = gid / n4;
    const int c = (gid % n4) << 2;
    float inv = __builtin_amdgcn_rcpf(denom[i]);
    float4 v = *(const float4*)(Hacc + (size_t)i * O + c);
    v.x *= inv; v.y *= inv; v.z *= inv; v.w *= inv;
    if (outf) {
        *(float4*)(outf + (size_t)i * O + c) = v;
    } else {
        ushort4 h;
        h.x = f2bf(v.x); h.y = f2bf(v.y); h.z = f2bf(v.z); h.w = f2bf(v.w);
        *(ushort4*)(outb + (size_t)i * O + c) = h;
    }
}

// ---------------- host ----------------
extern "C" void kernel_launch(void* const* d_in, const int* in_sizes, int n_in,
                              void* d_out, int out_size, void* d_ws, size_t ws_size,
                              hipStream_t stream)
{
    (void)in_sizes; (void)n_in; (void)out_size;
    const float* X = (const float*)d_in[0];
    const float* A = (const float*)d_in[1];
    const float* Wws[3] = {(const float*)d_in[2],  (const float*)d_in[8],  (const float*)d_in[14]};
    const float* Wbs[3] = {(const float*)d_in[3],  (const float*)d_in[9],  (const float*)d_in[15]};
    const float* tws[3] = {(const float*)d_in[4],  (const float*)d_in[10], (const float*)d_in[16]};
    const float* tbs[3] = {(const float*)d_in[5],  (const float*)d_in[11], (const float*)d_in[17]};
    const float* rws[3] = {(const float*)d_in[6],  (const float*)d_in[12], (const float*)d_in[18]};
    const float* rbs[3] = {(const float*)d_in[7],  (const float*)d_in[13], (const float*)d_in[19]};
    const int Ks[3] = {1024, 512, 256};
    const int Os[3] = {512, 256, 64};
    const int Zs[3] = {4, 8, 16};               // z-splits -> 1024 blocks each
    float* out = (float*)d_out;
    char* ws = (char*)d_ws;
    const size_t MB = (size_t)1 << 20;

    unsigned short* HbfX = (unsigned short*)(ws);             // 16 MB
    unsigned short* Hbf2 = (unsigned short*)(ws + 16 * MB);   // 8 MB
    unsigned short* Zt   = (unsigned short*)(ws + 24 * MB);   // 8 MB
    float*          Hacc = (float*)(ws + 32 * MB);            // 16 MB
    unsigned short* Wbf  = (unsigned short*)(ws + 48 * MB);   // 2 MB
    float* tv = (float*)(ws + 50 * MB);
    float* rv = tv + NN;
    float* dv = rv + NN;
    unsigned short* Abf = (unsigned short*)(ws + 51 * MB);    // 128 MB
    const bool useAbf = (ws_size >= 180 * MB);

    unsigned short* WbfL[3] = {Wbf, Wbf + 512 * 1024, Wbf + 512 * 1024 + 256 * 512};

    cvt_bf16<<<(NN * 1024) / 2048, 256, 0, stream>>>(X, HbfX);
    for (int L = 0; L < 3; ++L)
        cvt_bf16<<<(Os[L] * Ks[L]) / 2048, 256, 0, stream>>>(Wws[L], WbfL[L]);
    if (useAbf)
        cvt_bf16<<<(int)(((size_t)NN * NN) / 2048), 256, 0, stream>>>(A, Abf);

    const unsigned short* Hbf_in = HbfX;
    for (int L = 0; L < 3; ++L) {
        int K = Ks[L], O = Os[L];
        int zs = Zs[L];
        int kcount = NN / (zs * 32);
        proj_mfma<<<dim3(O / 64, NN / 128), 256, 0, stream>>>(
            Hbf_in, WbfL[L], Wbs[L], Zt, K, O);
        hipMemsetAsync(tv, 0, 96 * 1024, stream);          // tv, rv, dv
        tr_zt<<<dim3(NN / 256, O / 64), 256, 0, stream>>>(
            Zt, tws[L], tbs[L], rws[L], rbs[L], tv, rv);
        hipMemsetAsync(Hacc, 0, (size_t)NN * O * sizeof(float), stream);
        dim3 grid(O >= 128 ? O / 128 : 1, NN / 128, zs);
        if (useAbf) {
            if (O >= 128)
                attn_fused<128, unsigned short><<<grid, 256, 0, stream>>>(
                    Abf, Zt, tv, rv, Hacc, dv, O, kcount);
            else
                attn_fused<64, unsigned short><<<grid, 256, 0, stream>>>(
                    Abf, Zt, tv, rv, Hacc, dv, O, kcount);
        } else {
            if (O >= 128)
                attn_fused<128, float><<<grid, 256, 0, stream>>>(
                    A, Zt, tv, rv, Hacc, dv, O, kcount);
            else
                attn_fused<64, float><<<grid, 256, 0, stream>>>(
                    A, Zt, tv, rv, Hacc, dv, O, kcount);
        }
        float* outf = (L == 2) ? out : nullptr;
        unsigned short* outb = (L == 2) ? nullptr : Hbf2;
        norm_cvt<<<(NN / 256) * (O / 4), 256, 0, stream>>>(Hacc, dv, outf, outb, O);
        Hbf_in = Hbf2;
    }
}

// Round 5
// 953.967 us; speedup vs baseline: 3.7836x; 1.0504x over previous
//
#include <hip/hip_runtime.h>
#include <math.h>

#define NN 8192

typedef __attribute__((ext_vector_type(8))) short short8;
typedef __attribute__((ext_vector_type(4))) float f32x4;

__device__ __forceinline__ float bf2f(unsigned short u) {
    unsigned int x = ((unsigned int)u) << 16;
    return __builtin_bit_cast(float, x);
}
__device__ __forceinline__ unsigned short f2bf(float f) {
    unsigned int x = __builtin_bit_cast(unsigned int, f);
    x = x + 0x7FFFu + ((x >> 16) & 1u);
    return (unsigned short)(x >> 16);
}
__device__ __forceinline__ float fast_sigexp(float x) {
    float s = __builtin_amdgcn_rcpf(1.0f + __expf(-x));
    return __expf(s);
}
__device__ __forceinline__ void gload16(const void* g, void* l) {
    __builtin_amdgcn_global_load_lds(
        (const __attribute__((address_space(1))) unsigned int*)g,
        (__attribute__((address_space(3))) unsigned int*)l, 16, 0, 0);
}

// ---------------- fp32 -> bf16 conversion ----------------
__global__ __launch_bounds__(256) void cvt_bf16(
    const float* __restrict__ src, unsigned short* __restrict__ dst)
{
    size_t idx = ((size_t)blockIdx.x * 256 + threadIdx.x) * 8;
    float4 a = *(const float4*)(src + idx);
    float4 b = *(const float4*)(src + idx + 4);
    unsigned int w0 = (unsigned int)f2bf(a.x) | ((unsigned int)f2bf(a.y) << 16);
    unsigned int w1 = (unsigned int)f2bf(a.z) | ((unsigned int)f2bf(a.w) << 16);
    unsigned int w2 = (unsigned int)f2bf(b.x) | ((unsigned int)f2bf(b.y) << 16);
    unsigned int w3 = (unsigned int)f2bf(b.z) | ((unsigned int)f2bf(b.w) << 16);
    uint4 o = {w0, w1, w2, w3};
    *(uint4*)(dst + idx) = o;
}

// ---------------- raw 32B row loads + conversion helpers ----------------
template<typename AT> struct ARow;
template<> struct ARow<unsigned short> {
    struct Raw { uint4 a, b; };
    static __device__ __forceinline__ Raw ld(const unsigned short* p) {
        Raw r; r.a = ((const uint4*)p)[0]; r.b = ((const uint4*)p)[1]; return r;
    }
    static __device__ __forceinline__ void cvt(const Raw& r, float* d) {
        unsigned int wd[8] = {r.a.x, r.a.y, r.a.z, r.a.w, r.b.x, r.b.y, r.b.z, r.b.w};
        #pragma unroll
        for (int k = 0; k < 8; ++k) {
            d[2*k]   = __builtin_bit_cast(float, wd[k] << 16);
            d[2*k+1] = __builtin_bit_cast(float, wd[k] & 0xFFFF0000u);
        }
    }
};
template<> struct ARow<float> {
    struct Raw { float4 v[4]; };
    static __device__ __forceinline__ Raw ld(const float* p) {
        Raw r;
        r.v[0] = ((const float4*)p)[0]; r.v[1] = ((const float4*)p)[1];
        r.v[2] = ((const float4*)p)[2]; r.v[3] = ((const float4*)p)[3];
        return r;
    }
    static __device__ __forceinline__ void cvt(const Raw& r, float* d) {
        #pragma unroll
        for (int q = 0; q < 4; ++q) {
            d[4*q+0] = r.v[q].x; d[4*q+1] = r.v[q].y;
            d[4*q+2] = r.v[q].z; d[4*q+3] = r.v[q].w;
        }
    }
};
// stage 16 A elems (one 32B global read) into Ac as 8 dword LDS writes
template<typename AT> struct StageAc;
template<> struct StageAc<unsigned short> {
    static __device__ __forceinline__ void st(const unsigned short* g, unsigned short* l) {
        uint4 a = ((const uint4*)g)[0];
        uint4 b = ((const uint4*)g)[1];
        unsigned int* d = (unsigned int*)l;
        d[0]=a.x; d[1]=a.y; d[2]=a.z; d[3]=a.w;
        d[4]=b.x; d[5]=b.y; d[6]=b.z; d[7]=b.w;
    }
};
template<> struct StageAc<float> {
    static __device__ __forceinline__ void st(const float* g, unsigned short* l) {
        typename ARow<float>::Raw r = ARow<float>::ld(g);
        float v[16];
        ARow<float>::cvt(r, v);
        unsigned int* d = (unsigned int*)l;
        #pragma unroll
        for (int k = 0; k < 8; ++k)
            d[k] = (unsigned int)f2bf(v[2*k]) | ((unsigned int)f2bf(v[2*k+1]) << 16);
    }
};

// ---------------- projection GEMM (bf16 MFMA): Zt[o][i] = relu(H@W^T + b) ----------------
__global__ __launch_bounds__(256) void proj_mfma(
    const unsigned short* __restrict__ Hbf,
    const unsigned short* __restrict__ Wbf,
    const float* __restrict__ bias,
    unsigned short* __restrict__ Zt,
    int K, int O)
{
    constexpr int MT = 4, NT = 2;
    __shared__ unsigned short smem[8704];
    unsigned short* As = smem;
    unsigned short* Bs = smem + 4096;
    const int tid = threadIdx.x;
    const int w = tid >> 6;
    const int lane = tid & 63;
    const int quad = lane >> 4;
    const int m16 = lane & 15;
    const int i0 = blockIdx.y * 128;
    const int o0 = blockIdx.x * 64;
    const int wm = w & 1;
    const int wn = w >> 1;

    const char* gpa[2]; void* lpa[2];
    #pragma unroll
    for (int n = 0; n < 2; ++n) {
        int o16 = n * 256 + w * 64 + lane;
        int row = o16 >> 2, ch = o16 & 3;
        int sc = ch ^ ((row >> 1) & 3);
        gpa[n] = (const char*)(Hbf + (size_t)(i0 + row) * K) + sc * 16;
        lpa[n] = (char*)As + n * 4096 + w * 1024 + lane * 16;
    }
    const char* gpb; void* lpb;
    {
        int o16 = w * 64 + lane;
        int row = o16 >> 2, ch = o16 & 3;
        int sc = ch ^ ((row >> 1) & 3);
        gpb = (const char*)(Wbf + (size_t)(o0 + row) * K) + sc * 16;
        lpb = (char*)Bs + w * 1024 + lane * 16;
    }
    int aoff[MT], boff[NT];
    #pragma unroll
    for (int mt = 0; mt < MT; ++mt) {
        int row = wm * 64 + mt * 16 + m16;
        int sc = quad ^ ((row >> 1) & 3);
        aoff[mt] = row * 32 + sc * 8;
    }
    #pragma unroll
    for (int nt = 0; nt < NT; ++nt) {
        int row = wn * 32 + nt * 16 + m16;
        int sc = quad ^ ((row >> 1) & 3);
        boff[nt] = row * 32 + sc * 8;
    }
    f32x4 acc[MT][NT];
    #pragma unroll
    for (int mt = 0; mt < MT; ++mt)
        #pragma unroll
        for (int nt = 0; nt < NT; ++nt)
            acc[mt][nt] = (f32x4){0.f, 0.f, 0.f, 0.f};

    for (int k0 = 0; k0 < K; k0 += 32) {
        gload16(gpa[0], lpa[0]); gpa[0] += 64;
        gload16(gpa[1], lpa[1]); gpa[1] += 64;
        gload16(gpb, lpb); gpb += 64;
        __syncthreads();
        short8 af[MT], bf_[NT];
        #pragma unroll
        for (int mt = 0; mt < MT; ++mt) af[mt] = *(const short8*)(As + aoff[mt]);
        #pragma unroll
        for (int nt = 0; nt < NT; ++nt) bf_[nt] = *(const short8*)(Bs + boff[nt]);
        #pragma unroll
        for (int mt = 0; mt < MT; ++mt)
            #pragma unroll
            for (int nt = 0; nt < NT; ++nt)
                acc[mt][nt] = __builtin_amdgcn_mfma_f32_16x16x32_bf16(
                    af[mt], bf_[nt], acc[mt][nt], 0, 0, 0);
        __syncthreads();
    }
    #pragma unroll
    for (int nt = 0; nt < NT; ++nt) {
        int ol = wn * 32 + nt * 16 + m16;
        float bv = bias[o0 + ol];
        #pragma unroll
        for (int mt = 0; mt < MT; ++mt)
            #pragma unroll
            for (int rg = 0; rg < 4; ++rg) {
                int il = wm * 64 + mt * 16 + quad * 4 + rg;
                smem[ol * 136 + il] = f2bf(fmaxf(acc[mt][nt][rg] + bv, 0.f));
            }
    }
    __syncthreads();
    #pragma unroll
    for (int c = 0; c < 4; ++c) {
        int cc = c * 256 + tid;
        int ol = cc >> 4;
        int ic = (cc & 15) << 3;
        *(uint4*)(Zt + (size_t)(o0 + ol) * NN + i0 + ic) = *(const uint4*)&smem[ol * 136 + ic];
    }
}

// ---------------- t,r: column-split atomic dots over Zt ----------------
__global__ __launch_bounds__(256) void tr_zt(
    const unsigned short* __restrict__ Zt,
    const float* __restrict__ tw, const float* __restrict__ tb,
    const float* __restrict__ rw, const float* __restrict__ rb,
    float* __restrict__ t, float* __restrict__ r)
{
    const int i  = blockIdx.x * 256 + threadIdx.x;
    const int c0 = blockIdx.y * 64;
    float at = 0.f, ar = 0.f;
    for (int c = c0; c < c0 + 64; ++c) {
        float z = bf2f(Zt[(size_t)c * NN + i]);
        at = fmaf(z, tw[c], at);
        ar = fmaf(z, rw[c], ar);
    }
    if (blockIdx.y == 0) { at += tb[0]; ar += rb[0]; }
    atomicAdd(t + i, at);
    atomicAdd(r + i, ar);
}

// ---------------- fused attention: P on the fly + bf16 MFMA + denom ----------------
// Hacc[i,c] += sum_{j slice} p(i,j)*Z[c,j];  denom[i] += sum_j p(i,j) (x==0 only)
// 2-barrier pipeline: [compute P -> As] A [MFMA + stage next Ac/Bs/regs] B
template<int BN, typename AT>
__global__ __launch_bounds__(256) void attn_fused(
    const AT* __restrict__ A,
    const unsigned short* __restrict__ Zt,   // [O][NN] bf16
    const float* __restrict__ t, const float* __restrict__ r,
    float* __restrict__ Hacc, float* __restrict__ denom,
    int O, int kcount)
{
    constexpr int BM = 128, BK = 32;
    constexpr int MT = 4;              // WROWS=2
    constexpr int NT = BN / 32;        // WCOLS=2
    constexpr int NB = (BN * BK * 2) / 4096;
    constexpr int BNK = BN * BK;
    __shared__ unsigned short As[BM * BK];       // P tile (single-buffered)
    __shared__ unsigned short Bs[2][BNK];        // Zt tiles (double-buffered)
    __shared__ unsigned short Ac[BK * 130];      // A-col tile [j][i], stride 130 (conflict-free)
    const int tid  = threadIdx.x;
    const int w    = tid >> 6;
    const int lane = tid & 63;
    const int quad = lane >> 4;
    const int m16  = lane & 15;
    const int i0 = blockIdx.y * BM;
    const int c0 = blockIdx.x * BN;
    const int wm = w & 1;
    const int wn = w >> 1;
    const int jbase = blockIdx.z * kcount * BK;

    // compute-role: thread owns (row ci, 16-j half jh)
    const int ci = tid >> 1;
    const int jh = tid & 1;
    const float ri = r[i0 + ci];
    const int si = (ci >> 1) & 3;
    unsigned short* asw0 = As + ci * 32 + (((jh * 2)    ) ^ si) * 8;
    unsigned short* asw1 = As + ci * 32 + (((jh * 2) + 1) ^ si) * 8;
    // staging-role: thread stages A[j0+sj][i0 + sm*16 .. +16]
    const int sj = tid >> 3;
    const int sm = tid & 7;
    unsigned short* acw = Ac + sj * 130 + sm * 16;
    const AT* astage = A + (size_t)(jbase + sj) * NN + i0 + sm * 16;

    // Bs gload pointers
    const char* gpb[NB]; unsigned int lob[NB];
    #pragma unroll
    for (int n = 0; n < NB; ++n) {
        int o16 = n * 256 + w * 64 + lane;
        int row = o16 >> 2, ch = o16 & 3;
        int sc = ch ^ ((row >> 1) & 3);
        gpb[n] = (const char*)Zt + ((size_t)(c0 + row) * NN + jbase) * 2 + sc * 16;
        lob[n] = n * 4096 + w * 1024 + lane * 16;
    }
    int aoff[MT], boff[NT];
    #pragma unroll
    for (int mt = 0; mt < MT; ++mt) {
        int row = wm * 64 + mt * 16 + m16;
        int sc = quad ^ ((row >> 1) & 3);
        aoff[mt] = row * 32 + sc * 8;
    }
    #pragma unroll
    for (int nt = 0; nt < NT; ++nt) {
        int row = wn * (BN / 2) + nt * 16 + m16;
        int sc = quad ^ ((row >> 1) & 3);
        boff[nt] = row * 32 + sc * 8;
    }

    f32x4 acc[MT][NT];
    #pragma unroll
    for (int mt = 0; mt < MT; ++mt)
        #pragma unroll
        for (int nt = 0; nt < NT; ++nt)
            acc[mt][nt] = (f32x4){0.f, 0.f, 0.f, 0.f};

    const AT* arow = A + (size_t)(i0 + ci) * NN + jbase + jh * 16;
    const float* tptr = t + jbase + jh * 16;

    // prologue: stage j-block 0 (Ac, Bs[0], regs)
    #pragma unroll
    for (int n = 0; n < NB; ++n)
        gload16(gpb[n], (char*)Bs[0] + lob[n]);
    StageAc<AT>::st(astage, acw);
    typename ARow<AT>::Raw avr = ARow<AT>::ld(arow);
    float4 tvr0 = ((const float4*)tptr)[0];
    float4 tvr1 = ((const float4*)tptr)[1];
    float4 tvr2 = ((const float4*)tptr)[2];
    float4 tvr3 = ((const float4*)tptr)[3];
    __syncthreads();

    float rsum = 0.f;
    for (int kk = 0; kk < kcount; ++kk) {
        const int b = kk & 1;
        // ---- compute phase: p -> As (reads Ac + regs) ----
        float av[16], tvv[16];
        ARow<AT>::cvt(avr, av);
        tvv[0]=tvr0.x; tvv[1]=tvr0.y; tvv[2]=tvr0.z; tvv[3]=tvr0.w;
        tvv[4]=tvr1.x; tvv[5]=tvr1.y; tvv[6]=tvr1.z; tvv[7]=tvr1.w;
        tvv[8]=tvr2.x; tvv[9]=tvr2.y; tvv[10]=tvr2.z; tvv[11]=tvr2.w;
        tvv[12]=tvr3.x; tvv[13]=tvr3.y; tvv[14]=tvr3.z; tvv[15]=tvr3.w;
        unsigned int wd[8];
        #pragma unroll
        for (int e = 0; e < 16; ++e) {
            float aji = bf2f(Ac[(jh * 16 + e) * 130 + ci]);
            float x = fmaf(av[e], tvv[e], aji * ri);
            float p = fast_sigexp(x);
            rsum += p;
            if (e & 1) wd[e >> 1] |= ((unsigned int)f2bf(p)) << 16;
            else       wd[e >> 1]  = (unsigned int)f2bf(p);
        }
        {
            uint4 s0 = {wd[0], wd[1], wd[2], wd[3]};
            uint4 s1 = {wd[4], wd[5], wd[6], wd[7]};
            *(uint4*)asw0 = s0;
            *(uint4*)asw1 = s1;
        }
        __syncthreads();   // barrier A: As ready; prev MFMA reads done
        // ---- MFMA phase ----
        {
            const unsigned short* bsb = Bs[b];
            short8 af[MT], bf_[NT];
            #pragma unroll
            for (int mt = 0; mt < MT; ++mt) af[mt] = *(const short8*)(As + aoff[mt]);
            #pragma unroll
            for (int nt = 0; nt < NT; ++nt) bf_[nt] = *(const short8*)(bsb + boff[nt]);
            #pragma unroll
            for (int mt = 0; mt < MT; ++mt)
                #pragma unroll
                for (int nt = 0; nt < NT; ++nt)
                    acc[mt][nt] = __builtin_amdgcn_mfma_f32_16x16x32_bf16(
                        af[mt], bf_[nt], acc[mt][nt], 0, 0, 0);
        }
        // ---- stage next j-block ----
        if (kk + 1 < kcount) {
            #pragma unroll
            for (int n = 0; n < NB; ++n)
                gload16(gpb[n] + (size_t)(kk + 1) * 64, (char*)Bs[b ^ 1] + lob[n]);
            StageAc<AT>::st(astage + (size_t)(kk + 1) * BK * NN, acw);
            avr = ARow<AT>::ld(arow + (size_t)(kk + 1) * BK);
            const float* tp = tptr + (kk + 1) * BK;
            tvr0 = ((const float4*)tp)[0];
            tvr1 = ((const float4*)tp)[1];
            tvr2 = ((const float4*)tp)[2];
            tvr3 = ((const float4*)tp)[3];
        }
        __syncthreads();   // barrier B: Ac/Bs[next] ready; As reads done
    }

    // denom accumulation (unquantized fp32 row sums), x==0 blocks only
    rsum += __shfl_xor(rsum, 1);
    if (jh == 0 && blockIdx.x == 0)
        atomicAdd(denom + i0 + ci, rsum);

    // unnormalized atomic output
    const int colb = c0 + wn * (BN / 2) + m16;
    #pragma unroll
    for (int mt = 0; mt < MT; ++mt) {
        int rowb = i0 + wm * 64 + mt * 16 + quad * 4;
        #pragma unroll
        for (int rg = 0; rg < 4; ++rg) {
            float* orow = Hacc + (size_t)(rowb + rg) * O + colb;
            #pragma unroll
            for (int nt = 0; nt < NT; ++nt)
                atomicAdd(orow + nt * 16, acc[mt][nt][rg]);
        }
    }
}

// ---------------- normalize + emit (f32 out or bf16 next-layer input) ----------------
__global__ __launch_bounds__(256) void norm_cvt(
    const float* __restrict__ Hacc, const float* __restrict__ denom,
    float* __restrict__ outf, unsigned short* __restrict__ outb, int O)
{
    const int gid = blockIdx.x * 256 + threadIdx.x;
    const int n4 = O >> 2;
    const int i = gid / n4;
    const int c = (gid % n4) << 2;
    float inv = __builtin_amdgcn_rcpf(denom[i]);
    float4 v = *(const float4*)(Hacc + (size_t)i * O + c);
    v.x *= inv; v.y *= inv; v.z *= inv; v.w *= inv;
    if (outf) {
        *(float4*)(outf + (size_t)i * O + c) = v;
    } else {
        ushort4 h;
        h.x = f2bf(v.x); h.y = f2bf(v.y); h.z = f2bf(v.z); h.w = f2bf(v.w);
        *(ushort4*)(outb + (size_t)i * O + c) = h;
    }
}

// ---------------- host ----------------
extern "C" void kernel_launch(void* const* d_in, const int* in_sizes, int n_in,
                              void* d_out, int out_size, void* d_ws, size_t ws_size,
                              hipStream_t stream)
{
    (void)in_sizes; (void)n_in; (void)out_size;
    const float* X = (const float*)d_in[0];
    const float* A = (const float*)d_in[1];
    const float* Wws[3] = {(const float*)d_in[2],  (const float*)d_in[8],  (const float*)d_in[14]};
    const float* Wbs[3] = {(const float*)d_in[3],  (const float*)d_in[9],  (const float*)d_in[15]};
    const float* tws[3] = {(const float*)d_in[4],  (const float*)d_in[10], (const float*)d_in[16]};
    const float* tbs[3] = {(const float*)d_in[5],  (const float*)d_in[11], (const float*)d_in[17]};
    const float* rws[3] = {(const float*)d_in[6],  (const float*)d_in[12], (const float*)d_in[18]};
    const float* rbs[3] = {(const float*)d_in[7],  (const float*)d_in[13], (const float*)d_in[19]};
    const int Ks[3] = {1024, 512, 256};
    const int Os[3] = {512, 256, 64};
    const int Zs[3] = {8, 16, 16};     // z-splits -> 1024 blocks each
    float* out = (float*)d_out;
    char* ws = (char*)d_ws;
    const size_t MB = (size_t)1 << 20;

    unsigned short* HbfX = (unsigned short*)(ws);             // 16 MB
    unsigned short* Hbf2 = (unsigned short*)(ws + 16 * MB);   // 8 MB
    unsigned short* Zt   = (unsigned short*)(ws + 24 * MB);   // 8 MB
    float*          Hacc = (float*)(ws + 32 * MB);            // 16 MB
    unsigned short* Wbf  = (unsigned short*)(ws + 48 * MB);   // 2 MB
    float* tv = (float*)(ws + 50 * MB);
    float* rv = tv + NN;
    float* dv = rv + NN;
    unsigned short* Abf = (unsigned short*)(ws + 51 * MB);    // 128 MB
    const bool useAbf = (ws_size >= 180 * MB);

    unsigned short* WbfL[3] = {Wbf, Wbf + 512 * 1024, Wbf + 512 * 1024 + 256 * 512};

    cvt_bf16<<<(NN * 1024) / 2048, 256, 0, stream>>>(X, HbfX);
    for (int L = 0; L < 3; ++L)
        cvt_bf16<<<(Os[L] * Ks[L]) / 2048, 256, 0, stream>>>(Wws[L], WbfL[L]);
    if (useAbf)
        cvt_bf16<<<(int)(((size_t)NN * NN) / 2048), 256, 0, stream>>>(A, Abf);

    const unsigned short* Hbf_in = HbfX;
    for (int L = 0; L < 3; ++L) {
        int K = Ks[L], O = Os[L];
        int zs = Zs[L];
        int kcount = NN / (zs * 32);
        proj_mfma<<<dim3(O / 64, NN / 128), 256, 0, stream>>>(
            Hbf_in, WbfL[L], Wbs[L], Zt, K, O);
        hipMemsetAsync(tv, 0, 96 * 1024, stream);          // tv, rv, dv
        tr_zt<<<dim3(NN / 256, O / 64), 256, 0, stream>>>(
            Zt, tws[L], tbs[L], rws[L], rbs[L], tv, rv);
        hipMemsetAsync(Hacc, 0, (size_t)NN * O * sizeof(float), stream);
        int gx = (O >= 256) ? O / 256 : 1;
        dim3 grid(gx, NN / 128, zs);
        if (useAbf) {
            if (O >= 256)
                attn_fused<256, unsigned short><<<grid, 256, 0, stream>>>(
                    Abf, Zt, tv, rv, Hacc, dv, O, kcount);
            else
                attn_fused<64, unsigned short><<<grid, 256, 0, stream>>>(
                    Abf, Zt, tv, rv, Hacc, dv, O, kcount);
        } else {
            if (O >= 256)
                attn_fused<256, float><<<grid, 256, 0, stream>>>(
                    A, Zt, tv, rv, Hacc, dv, O, kcount);
            else
                attn_fused<64, float><<<grid, 256, 0, stream>>>(
                    A, Zt, tv, rv, Hacc, dv, O, kcount);
        }
        float* outf = (L == 2) ? out : nullptr;
        unsigned short* outb = (L == 2) ? nullptr : Hbf2;
        norm_cvt<<<(NN / 256) * (O / 4), 256, 0, stream>>>(Hacc, dv, outf, outb, O);
        Hbf_in = Hbf2;
    }
}